// Round 17
// baseline (1177.476 us; speedup 1.0000x reference)
//
#include <hip/hip_runtime.h>
#include <hip/hip_bf16.h>
#include <math.h>

#define G_GRAPHS 256
#define EPG 2048
#define E_TOT 524288
#define HF 256
#define FIN 128

// ============================================================================
__global__ void init_cur(int* __restrict__ cur) {
    int i = blockIdx.x * blockDim.x + threadIdx.x;
    if (i < G_GRAPHS * 256) cur[i] = i & 255;
}

// ---------------------------------------------------------------------------
// C[N x 256] = A[N x K] @ W[K x 256], fp32, k-ascending accumulation.
// ---------------------------------------------------------------------------
template <int K>
__global__ __launch_bounds__(256)
void gemm_t4(const float* __restrict__ A, const float* __restrict__ W,
             float* __restrict__ C) {
    __shared__ float As[64][68];
    __shared__ float Ws[64][68];
    const int tid = threadIdx.x;
    const int tx = tid & 15;
    const int ty = tid >> 4;
    const int r0 = blockIdx.x * 64;
    const int c0 = blockIdx.y * 64;
    float acc[4][4] = {{0.f}};
    for (int k0 = 0; k0 < K; k0 += 64) {
        for (int i = tid; i < 4096; i += 256) {
            int r = i >> 6, kk = i & 63;
            As[kk][r] = A[(size_t)(r0 + r) * K + (k0 + kk)];
        }
        for (int i = tid; i < 4096; i += 256) {
            int kk = i >> 6, c = i & 63;
            Ws[kk][c] = W[(size_t)(k0 + kk) * 256 + (c0 + c)];
        }
        __syncthreads();
#pragma unroll 8
        for (int kk = 0; kk < 64; ++kk) {
            float4 av = *(const float4*)&As[kk][ty * 4];
            float4 wv = *(const float4*)&Ws[kk][tx * 4];
            acc[0][0] += av.x * wv.x; acc[0][1] += av.x * wv.y;
            acc[0][2] += av.x * wv.z; acc[0][3] += av.x * wv.w;
            acc[1][0] += av.y * wv.x; acc[1][1] += av.y * wv.y;
            acc[1][2] += av.y * wv.z; acc[1][3] += av.y * wv.w;
            acc[2][0] += av.z * wv.x; acc[2][1] += av.z * wv.y;
            acc[2][2] += av.z * wv.z; acc[2][3] += av.z * wv.w;
            acc[3][0] += av.w * wv.x; acc[3][1] += av.w * wv.y;
            acc[3][2] += av.w * wv.z; acc[3][3] += av.w * wv.w;
        }
        __syncthreads();
    }
#pragma unroll
    for (int i = 0; i < 4; ++i) {
        float4 v = make_float4(acc[i][0], acc[i][1], acc[i][2], acc[i][3]);
        *(float4*)&C[(size_t)(r0 + ty * 4 + i) * 256 + c0 + tx * 4] = v;
    }
}

// ---------------------------------------------------------------------------
// Per-graph CSR by dst (ascending edge order), deg, dinv.
// ---------------------------------------------------------------------------
__global__ __launch_bounds__(256)
void csr_build(const int* __restrict__ ei, const int* __restrict__ cur, int npg,
               int* __restrict__ degS, float* __restrict__ dinvS,
               int* __restrict__ startsS, int* __restrict__ slotsS) {
    __shared__ int cul[EPG];
    __shared__ int cvl[EPG];
    __shared__ int cnt[256];
    __shared__ int st[256];
    const int g = blockIdx.x;
    const int t = threadIdx.x;
    if (t < npg) cnt[t] = 0;
    __syncthreads();
    for (int e = t; e < EPG; e += 256) {
        size_t idx = (size_t)g * EPG + e;
        int ul = ei[idx] - g * 256;
        int vl = ei[E_TOT + idx] - g * 256;
        int cu = cur[g * 256 + ul];
        int cv = cur[g * 256 + vl];
        if (cu >= 0 && cv >= 0) { atomicAdd(&cnt[cv], 1); }
        else cv = -1;
        cul[e] = cu;
        cvl[e] = cv;
    }
    __syncthreads();
    if (t == 0) {
        int run = 0;
        for (int i = 0; i < npg; ++i) { st[i] = run; run += cnt[i]; }
    }
    __syncthreads();
    if (t < npg) {
        int node = g * npg + t;
        degS[node] = cnt[t] + 1;
        dinvS[node] = 1.0f / sqrtf((float)(cnt[t] + 1));
        int base = g * EPG + st[t];
        startsS[node] = base;
        int c = base;
        for (int e = 0; e < EPG; ++e)
            if (cvl[e] == t) slotsS[c++] = g * npg + cul[e];  // ascending e
    }
}

// ---------------------------------------------------------------------------
// LDS-staged conv: block = (graph, feature-half). Tile npg x 128 feats in LDS.
// Waves 0-1 handle node n, waves 2-3 node n+1. Same accumulation order as
// before (ascending CSR slots) -> bit-identical H2.
// ---------------------------------------------------------------------------
__global__ __launch_bounds__(256, 1)
void agg_tile(const int* __restrict__ degS, const float* __restrict__ dinvS,
              const int* __restrict__ startsS, const int* __restrict__ slotsS,
              const float* __restrict__ HL, float* __restrict__ H2,
              const float* __restrict__ bias, int npg) {
    extern __shared__ float smem[];
    float* tile = smem;              // npg * 128
    float* dinvL = smem + npg * 128; // npg
    const int g = blockIdx.x;
    const int f0 = blockIdx.y * 128;
    const int t = threadIdx.x;
    const int nodeBase = g * npg;
    for (int i = t; i < npg * 128; i += 256) {
        int n = i >> 7, f = i & 127;
        tile[i] = HL[(size_t)(nodeBase + n) * 256 + f0 + f];
    }
    if (t < npg) dinvL[t] = dinvS[nodeBase + t];
    __syncthreads();
    const int f = t & 127;
    const int sub = t >> 7;          // 0/1: which node of the pair
    const float bb = bias[f0 + f];
    for (int n0 = 0; n0 < npg; n0 += 2) {
        const int n = n0 + sub;
        const int node = nodeBase + n;
        const int cntE = degS[node] - 1;
        const int s0 = startsS[node];
        float acc = 0.f;
        for (int j = 0; j < cntE; ++j) {
            int sl = slotsS[s0 + j] - nodeBase;   // local src id
            acc += dinvL[sl] * tile[sl * 128 + f];
        }
        float degF = (float)(cntE + 1);
        float v = acc * dinvL[n] + tile[n * 128 + f] / degF + bb;
        H2[(size_t)node * 256 + f0 + f] = fmaxf(v, 0.f);
    }
}

// ---------------------------------------------------------------------------
// score = tanh(H2.w/||w||): one wave per node; reduction order bit-identical
// to R16's agg_score (per-lane strided partials + shfl butterfly).
// ---------------------------------------------------------------------------
__global__ __launch_bounds__(256)
void score_k(const float* __restrict__ H2, const float* __restrict__ pw,
             float* __restrict__ score) {
    const int lane = threadIdx.x & 63;
    const int wv = threadIdx.x >> 6;
    const int node = blockIdx.x * 4 + wv;
    float pr = 0.f, s2p = 0.f;
    for (int j = 0; j < 4; ++j) {
        int f = lane + 64 * j;
        float w = pw[f];
        pr += H2[(size_t)node * 256 + f] * w;
        s2p += w * w;
    }
    for (int off = 32; off; off >>= 1) {
        pr += __shfl_down(pr, off, 64);
        s2p += __shfl_down(s2p, off, 64);
    }
    s2p = __shfl(s2p, 0, 64);
    if (lane == 0) score[node] = tanhf(pr / sqrtf(s2p));
}

// ---------------------------------------------------------------------------
__global__ __launch_bounds__(256)
void topk_cur(const float* __restrict__ score, int npg, int k,
              int* __restrict__ kept, int* __restrict__ cur) {
    __shared__ float ss[256];
    __shared__ int si_[256];
    __shared__ int rankOf[256];
    const int g = blockIdx.x;
    const int t = threadIdx.x;
    if (t < npg) { ss[t] = score[g * npg + t]; si_[t] = t; }
    else         { ss[t] = -INFINITY; si_[t] = 0x7FFFFFFF; }
    for (int size = 2; size <= 256; size <<= 1) {
        for (int stride = size >> 1; stride > 0; stride >>= 1) {
            __syncthreads();
            int i = t, j = t ^ stride;
            if (j > i) {
                float a = ss[i], b = ss[j];
                int ia = si_[i], ib = si_[j];
                bool inOrder = (a > b) || (a == b && ia < ib);
                bool desc = ((i & size) == 0);
                if (desc ? !inOrder : inOrder) {
                    ss[i] = b; ss[j] = a; si_[i] = ib; si_[j] = ia;
                }
            }
        }
    }
    __syncthreads();
    rankOf[t] = -1;
    __syncthreads();
    if (t < k) {
        kept[g * k + t] = g * npg + si_[t];
        rankOf[si_[t]] = t;
    }
    __syncthreads();
    {
        int v = g * 256 + t;
        int c = cur[v];
        cur[v] = (c >= 0) ? rankOf[c] : -1;
    }
}

__global__ __launch_bounds__(256)
void pool_gather(const int* __restrict__ kept, const float* __restrict__ score,
                 const float* __restrict__ H2, float* __restrict__ OUT) {
    const int j = blockIdx.x;
    const int t = threadIdx.x;
    const int o = kept[j];
    OUT[(size_t)j * 256 + t] = H2[(size_t)o * 256 + t] * score[o];
}

__global__ __launch_bounds__(256)
void readout(const float* __restrict__ X, int k, float* __restrict__ outacc,
             int first) {
    const int g = blockIdx.x;
    const int t = threadIdx.x;
    const float* base = X + (size_t)g * k * 256 + t;
    float mx = -INFINITY, sm = 0.f;
    for (int n = 0; n < k; ++n) {
        float vv = base[(size_t)n * 256];
        mx = fmaxf(mx, vv);
        sm += vv;
    }
    float mean = sm / (float)k;
    if (first) {
        outacc[g * 512 + t] = mx;
        outacc[g * 512 + 256 + t] = mean;
    } else {
        outacc[g * 512 + t] += mx;
        outacc[g * 512 + 256 + t] += mean;
    }
}

__global__ __launch_bounds__(256)
void mlp_head(const float* __restrict__ outacc,
              const float* __restrict__ l1w, const float* __restrict__ l1b,
              const float* __restrict__ l2w, const float* __restrict__ l2b,
              const float* __restrict__ l3w, const float* __restrict__ l3b,
              float* __restrict__ out) {
    __shared__ float row[512];
    __shared__ float h1[256];
    __shared__ float h2[128];
    const int g = blockIdx.x;
    const int t = threadIdx.x;
    row[t] = outacc[g * 512 + t];
    row[256 + t] = outacc[g * 512 + 256 + t];
    __syncthreads();
    {
        float a = l1b[t];
        for (int j = 0; j < 512; ++j) a += row[j] * l1w[j * 256 + t];
        h1[t] = fmaxf(a, 0.f);
    }
    __syncthreads();
    if (t < 128) {
        float a2 = l2b[t];
        for (int j = 0; j < 256; ++j) a2 += h1[j] * l2w[j * 128 + t];
        h2[t] = fmaxf(a2, 0.f);
    }
    __syncthreads();
    if (t == 0) {
        float l0 = l3b[0], l1 = l3b[1];
        for (int j = 0; j < 128; ++j) {
            float h = h2[j];
            l0 += h * l3w[j * 2 + 0];
            l1 += h * l3w[j * 2 + 1];
        }
        float m = fmaxf(l0, l1);
        float lse = m + logf(expf(l0 - m) + expf(l1 - m));
        out[g * 2 + 0] = l0 - lse;
        out[g * 2 + 1] = l1 - lse;
    }
}

// ============================================================================
// Fallback: proven R15 monolith (used only if ws_size is too small)
// ============================================================================
__global__ __launch_bounds__(256, 1)
void gnn_mono(const float* __restrict__ x, const int* __restrict__ ei,
              const float* __restrict__ gw0, const float* __restrict__ gb0,
              const float* __restrict__ gw1, const float* __restrict__ gb1,
              const float* __restrict__ gw2, const float* __restrict__ gb2,
              const float* __restrict__ pw0, const float* __restrict__ pw1,
              const float* __restrict__ pw2,
              const float* __restrict__ l1w, const float* __restrict__ l1b,
              const float* __restrict__ l2w, const float* __restrict__ l2b,
              const float* __restrict__ l3w, const float* __restrict__ l3b,
              float* __restrict__ out, float* __restrict__ ws) {
    const int g = blockIdx.x;
    const int t = threadIdx.x;
    float* P = ws + (size_t)g * HF * 256;
    float* Q = ws + (size_t)G_GRAPHS * HF * 256 + (size_t)g * HF * 256;
    __shared__ int   eb[EPG];
    __shared__ int   slots[EPG];
    __shared__ int   curID[256];
    __shared__ int   cntL[256];
    __shared__ int   startL[256];
    __shared__ float degF[256];
    __shared__ float dinv[256];
    __shared__ float sa[256];
    __shared__ float ss[256];
    __shared__ int   si_[256];
    __shared__ float scoreV[256];
    __shared__ int   kept[128];
    __shared__ int   rankOf[256];
    __shared__ float row[512];
    for (int e = t; e < EPG; e += 256) {
        size_t idx = (size_t)g * EPG + e;
        eb[e] = ((ei[idx] - g * 256) << 8) | (ei[E_TOT + idx] - g * 256);
    }
    curID[t] = t;
    float accMx = 0.f, accMn = 0.f;
    const float* GW[3] = {gw0, gw1, gw2};
    const float* GB[3] = {gb0, gb1, gb2};
    const float* PW[3] = {pw0, pw1, pw2};
    const int kk[3] = {128, 64, 32};
    int npg = 256;
    __syncthreads();
    for (int s = 0; s < 3; ++s) {
        const int knext = kk[s];
        {
            const float* Wp = GW[s];
            const int K = (s == 0) ? FIN : HF;
            for (int n = 0; n < npg; ++n) {
                if (s == 0) { if (t < FIN) sa[t] = x[(size_t)(g * 256 + n) * FIN + t]; }
                else sa[t] = P[(size_t)n * HF + t];
                __syncthreads();
                float a = 0.f;
                for (int k2 = 0; k2 < K; ++k2) a += sa[k2] * Wp[k2 * HF + t];
                Q[(size_t)n * HF + t] = a;
                __syncthreads();
            }
        }
        cntL[t] = 0;
        __syncthreads();
        for (int e = t; e < EPG; e += 256) {
            int p = eb[e];
            int cu = curID[p >> 8], cv = curID[p & 255];
            if (cu >= 0 && cv >= 0) atomicAdd(&cntL[cv], 1);
        }
        __syncthreads();
        if (t == 0) { int run = 0; for (int i = 0; i < npg; ++i) { startL[i] = run; run += cntL[i]; } }
        __syncthreads();
        if (t < npg) {
            float d = (float)cntL[t] + 1.0f;
            degF[t] = d;
            dinv[t] = 1.0f / sqrtf(d);
            int c = startL[t];
            for (int e = 0; e < EPG; ++e) {
                int p = eb[e];
                int cu = curID[p >> 8], cv = curID[p & 255];
                if (cu >= 0 && cv >= 0 && cv == t) slots[c++] = e;
            }
        }
        __syncthreads();
        {
            const float bb = GB[s][t];
            for (int n = 0; n < npg; ++n) {
                float acc = 0.f;
                const int s0 = startL[n], s1 = s0 + cntL[n];
                for (int j = s0; j < s1; ++j) {
                    int scur = curID[eb[slots[j]] >> 8];
                    acc += dinv[scur] * Q[(size_t)scur * HF + t];
                }
                float v = acc * dinv[n] + Q[(size_t)n * HF + t] / degF[n] + bb;
                P[(size_t)n * HF + t] = fmaxf(v, 0.f);
            }
        }
        __syncthreads();
        {
            const float* pwp = PW[s];
            const int lane = t & 63, wv = t >> 6;
            float s2p = 0.f;
            for (int j = 0; j < 4; ++j) { float w = pwp[lane + 64 * j]; s2p += w * w; }
            for (int off = 32; off; off >>= 1) s2p += __shfl_down(s2p, off, 64);
            s2p = __shfl(s2p, 0, 64);
            const float nw = sqrtf(s2p);
            for (int n = wv; n < npg; n += 4) {
                float pr = 0.f;
                for (int j = 0; j < 4; ++j) { int f = lane + 64 * j; pr += P[(size_t)n * HF + f] * pwp[f]; }
                for (int off = 32; off; off >>= 1) pr += __shfl_down(pr, off, 64);
                if (lane == 0) scoreV[n] = tanhf(pr / nw);
            }
        }
        __syncthreads();
        if (t < npg) { ss[t] = scoreV[t]; si_[t] = t; }
        else         { ss[t] = -INFINITY; si_[t] = 0x7FFFFFFF; }
        for (int size = 2; size <= 256; size <<= 1) {
            for (int stride = size >> 1; stride > 0; stride >>= 1) {
                __syncthreads();
                int i = t, j = t ^ stride;
                if (j > i) {
                    float a = ss[i], b = ss[j];
                    int ia = si_[i], ib = si_[j];
                    bool inOrder = (a > b) || (a == b && ia < ib);
                    bool desc = ((i & size) == 0);
                    if (desc ? !inOrder : inOrder) { ss[i] = b; ss[j] = a; si_[i] = ib; si_[j] = ia; }
                }
            }
        }
        __syncthreads();
        if (t < knext) kept[t] = si_[t];
        __syncthreads();
        {
            float mx = -INFINITY, sm = 0.f;
            for (int n = 0; n < knext; ++n) {
                int o = kept[n];
                float vv = P[(size_t)o * HF + t] * scoreV[o];
                Q[(size_t)n * HF + t] = vv;
                mx = fmaxf(mx, vv);
                sm += vv;
            }
            accMx += mx;
            accMn += sm / (float)knext;
        }
        rankOf[t] = -1;
        __syncthreads();
        if (t < knext) rankOf[kept[t]] = t;
        __syncthreads();
        { int c = curID[t]; curID[t] = (c >= 0) ? rankOf[c] : -1; }
        __syncthreads();
        { float* tmp = P; P = Q; Q = tmp; }
        npg = knext;
    }
    row[t] = accMx;
    row[256 + t] = accMn;
    __syncthreads();
    { float a = l1b[t]; for (int j = 0; j < 512; ++j) a += row[j] * l1w[j * 256 + t]; scoreV[t] = fmaxf(a, 0.f); }
    __syncthreads();
    if (t < 128) { float a2 = l2b[t]; for (int j = 0; j < 256; ++j) a2 += scoreV[j] * l2w[j * 128 + t]; sa[t] = fmaxf(a2, 0.f); }
    __syncthreads();
    if (t == 0) {
        float l0 = l3b[0], l1 = l3b[1];
        for (int j = 0; j < 128; ++j) { float h = sa[j]; l0 += h * l3w[j * 2 + 0]; l1 += h * l3w[j * 2 + 1]; }
        float m = fmaxf(l0, l1);
        float lse = m + logf(expf(l0 - m) + expf(l1 - m));
        out[g * 2 + 0] = l0 - lse;
        out[g * 2 + 1] = l1 - lse;
    }
}

// ============================================================================
extern "C" void kernel_launch(void* const* d_in, const int* in_sizes, int n_in,
                              void* d_out, int out_size, void* d_ws, size_t ws_size,
                              hipStream_t stream) {
    const float* x   = (const float*)d_in[0];
    const int*   ei  = (const int*)d_in[1];
    const float* gw0 = (const float*)d_in[3];
    const float* gb0 = (const float*)d_in[4];
    const float* gw1 = (const float*)d_in[5];
    const float* gb1 = (const float*)d_in[6];
    const float* gw2 = (const float*)d_in[7];
    const float* gb2 = (const float*)d_in[8];
    const float* pw0 = (const float*)d_in[9];
    const float* pw1 = (const float*)d_in[10];
    const float* pw2 = (const float*)d_in[11];
    const float* l1w = (const float*)d_in[12];
    const float* l1b = (const float*)d_in[13];
    const float* l2w = (const float*)d_in[14];
    const float* l2b = (const float*)d_in[15];
    const float* l3w = (const float*)d_in[16];
    const float* l3b = (const float*)d_in[17];
    float* out = (float*)d_out;

    const size_t SLAB = (size_t)65536 * 256;
    char* p = (char*)d_ws;
    float* P      = (float*)p; p += SLAB * 4;
    float* Q      = (float*)p; p += SLAB * 4;
    int*   cur    = (int*)p;   p += (size_t)65536 * 4;
    int*   degS   = (int*)p;   p += (size_t)65536 * 4;
    float* dinvS  = (float*)p; p += (size_t)65536 * 4;
    int*   starts = (int*)p;   p += (size_t)65536 * 4;
    int*   slotsS = (int*)p;   p += (size_t)E_TOT * 4;
    float* score  = (float*)p; p += (size_t)65536 * 4;
    int*   kept   = (int*)p;   p += (size_t)32768 * 4;
    float* outacc = (float*)p; p += (size_t)G_GRAPHS * 512 * 4;
    const size_t needed = (size_t)(p - (char*)d_ws);

    if (ws_size < needed) {
        gnn_mono<<<G_GRAPHS, 256, 0, stream>>>(
            x, ei, gw0, gb0, gw1, gb1, gw2, gb2, pw0, pw1, pw2,
            l1w, l1b, l2w, l2b, l3w, l3b, out, (float*)d_ws);
        return;
    }

    init_cur<<<(G_GRAPHS * 256 + 255) / 256, 256, 0, stream>>>(cur);

    const int   npg[3] = {256, 128, 64};
    const int   kk[3]  = {128, 64, 32};
    const int   Ns[3]  = {65536, 32768, 16384};
    const float* GW[3] = {gw0, gw1, gw2};
    const float* GB[3] = {gb0, gb1, gb2};
    const float* PW[3] = {pw0, pw1, pw2};

    float* HLs[3]   = {P, Q, P};
    float* H2s[3]   = {Q, P, Q};
    float* POOLs[3] = {P, Q, P};

    for (int s = 0; s < 3; ++s) {
        const int n = Ns[s];
        const int k = kk[s];
        // 1) GEMM
        if (s == 0) {
            dim3 grid(n / 64, 4);
            gemm_t4<FIN><<<grid, 256, 0, stream>>>(x, GW[s], HLs[s]);
        } else {
            dim3 grid(n / 64, 4);
            gemm_t4<HF><<<grid, 256, 0, stream>>>(POOLs[s - 1], GW[s], HLs[s]);
        }
        // 2) CSR
        csr_build<<<G_GRAPHS, 256, 0, stream>>>(ei, cur, npg[s],
                                                degS, dinvS, starts, slotsS);
        // 3) conv (LDS graph-tile) + score
        {
            dim3 grid(G_GRAPHS, 2);
            size_t smem = (size_t)(npg[s] * 128 + npg[s]) * 4;
            agg_tile<<<grid, 256, smem, stream>>>(degS, dinvS, starts, slotsS,
                                                  HLs[s], H2s[s], GB[s], npg[s]);
        }
        score_k<<<n / 4, 256, 0, stream>>>(H2s[s], PW[s], score);
        // 4) top-k + cur update
        topk_cur<<<G_GRAPHS, 256, 0, stream>>>(score, npg[s], k, kept, cur);
        // 5) pool
        pool_gather<<<G_GRAPHS * k, 256, 0, stream>>>(kept, score, H2s[s], POOLs[s]);
        // 6) readout
        readout<<<G_GRAPHS, 256, 0, stream>>>(POOLs[s], k, outacc, s == 0 ? 1 : 0);
    }

    mlp_head<<<G_GRAPHS, 256, 0, stream>>>(outacc, l1w, l1b, l2w, l2b, l3w, l3b, out);
}

// Round 18
// 979.161 us; speedup vs baseline: 1.2025x; 1.2025x over previous
//
#include <hip/hip_runtime.h>
#include <hip/hip_bf16.h>
#include <math.h>

#define G_GRAPHS 256
#define EPG 2048
#define E_TOT 524288
#define HF 256
#define FIN 128

// ============================================================================
__global__ void init_cur(int* __restrict__ cur) {
    int i = blockIdx.x * blockDim.x + threadIdx.x;
    if (i < G_GRAPHS * 256) cur[i] = i & 255;
}

// ---------------------------------------------------------------------------
// C[N x 256] = A[N x K] @ W[K x 256], fp32, k-ascending accumulation.
// ---------------------------------------------------------------------------
template <int K>
__global__ __launch_bounds__(256)
void gemm_t4(const float* __restrict__ A, const float* __restrict__ W,
             float* __restrict__ C) {
    __shared__ float As[64][68];
    __shared__ float Ws[64][68];
    const int tid = threadIdx.x;
    const int tx = tid & 15;
    const int ty = tid >> 4;
    const int r0 = blockIdx.x * 64;
    const int c0 = blockIdx.y * 64;
    float acc[4][4] = {{0.f}};
    for (int k0 = 0; k0 < K; k0 += 64) {
        for (int i = tid; i < 4096; i += 256) {
            int r = i >> 6, kk = i & 63;
            As[kk][r] = A[(size_t)(r0 + r) * K + (k0 + kk)];
        }
        for (int i = tid; i < 4096; i += 256) {
            int kk = i >> 6, c = i & 63;
            Ws[kk][c] = W[(size_t)(k0 + kk) * 256 + (c0 + c)];
        }
        __syncthreads();
#pragma unroll 8
        for (int kk = 0; kk < 64; ++kk) {
            float4 av = *(const float4*)&As[kk][ty * 4];
            float4 wv = *(const float4*)&Ws[kk][tx * 4];
            acc[0][0] += av.x * wv.x; acc[0][1] += av.x * wv.y;
            acc[0][2] += av.x * wv.z; acc[0][3] += av.x * wv.w;
            acc[1][0] += av.y * wv.x; acc[1][1] += av.y * wv.y;
            acc[1][2] += av.y * wv.z; acc[1][3] += av.y * wv.w;
            acc[2][0] += av.z * wv.x; acc[2][1] += av.z * wv.y;
            acc[2][2] += av.z * wv.z; acc[2][3] += av.z * wv.w;
            acc[3][0] += av.w * wv.x; acc[3][1] += av.w * wv.y;
            acc[3][2] += av.w * wv.z; acc[3][3] += av.w * wv.w;
        }
        __syncthreads();
    }
#pragma unroll
    for (int i = 0; i < 4; ++i) {
        float4 v = make_float4(acc[i][0], acc[i][1], acc[i][2], acc[i][3]);
        *(float4*)&C[(size_t)(r0 + ty * 4 + i) * 256 + c0 + tx * 4] = v;
    }
}

// ---------------------------------------------------------------------------
// Per-graph CSR by dst (ascending edge order), deg, dinv.
// ---------------------------------------------------------------------------
__global__ __launch_bounds__(256)
void csr_build(const int* __restrict__ ei, const int* __restrict__ cur, int npg,
               int* __restrict__ degS, float* __restrict__ dinvS,
               int* __restrict__ startsS, int* __restrict__ slotsS) {
    __shared__ int cul[EPG];
    __shared__ int cvl[EPG];
    __shared__ int cnt[256];
    __shared__ int st[256];
    const int g = blockIdx.x;
    const int t = threadIdx.x;
    if (t < npg) cnt[t] = 0;
    __syncthreads();
    for (int e = t; e < EPG; e += 256) {
        size_t idx = (size_t)g * EPG + e;
        int ul = ei[idx] - g * 256;
        int vl = ei[E_TOT + idx] - g * 256;
        int cu = cur[g * 256 + ul];
        int cv = cur[g * 256 + vl];
        if (cu >= 0 && cv >= 0) { atomicAdd(&cnt[cv], 1); }
        else cv = -1;
        cul[e] = cu;
        cvl[e] = cv;
    }
    __syncthreads();
    if (t == 0) {
        int run = 0;
        for (int i = 0; i < npg; ++i) { st[i] = run; run += cnt[i]; }
    }
    __syncthreads();
    if (t < npg) {
        int node = g * npg + t;
        degS[node] = cnt[t] + 1;
        dinvS[node] = 1.0f / sqrtf((float)(cnt[t] + 1));
        int base = g * EPG + st[t];
        startsS[node] = base;
        int c = base;
        for (int e = 0; e < EPG; ++e)
            if (cvl[e] == t) slotsS[c++] = g * npg + cul[e];  // ascending e
    }
}

// ---------------------------------------------------------------------------
// conv + relu + pool score (R16-proven shape) with XCD-locality swizzle:
// node = (b & 7) * (N/8) + (b >> 3) keeps each graph's blocks on ONE XCD
// (consecutive blockIdx round-robin across the 8 XCDs), so the graph's HL
// tile stays in that XCD's L2. Arithmetic order per node unchanged.
// ---------------------------------------------------------------------------
__global__ __launch_bounds__(256)
void agg_score(const int* __restrict__ degS, const float* __restrict__ dinvS,
               const int* __restrict__ startsS, const int* __restrict__ slotsS,
               const float* __restrict__ HL, float* __restrict__ H2,
               const float* __restrict__ bias, const float* __restrict__ pw,
               float* __restrict__ score, int nOver8) {
    __shared__ float vrow[256];
    const int node = (blockIdx.x & 7) * nOver8 + (blockIdx.x >> 3);
    const int t = threadIdx.x;
    const int cntE = degS[node] - 1;
    const float degF = (float)degS[node];
    const float dn = dinvS[node];
    const int s0 = startsS[node];
    float acc = 0.f;
    for (int j = 0; j < cntE; ++j) {
        int srcg = slotsS[s0 + j];
        acc += dinvS[srcg] * HL[(size_t)srcg * 256 + t];
    }
    float v = acc * dn + HL[(size_t)node * 256 + t] / degF + bias[t];
    v = fmaxf(v, 0.f);
    H2[(size_t)node * 256 + t] = v;
    vrow[t] = v;
    __syncthreads();
    if (t < 64) {
        const int lane = t;
        float pr = 0.f, s2p = 0.f;
        for (int j = 0; j < 4; ++j) {
            int f = lane + 64 * j;
            float w = pw[f];
            pr += vrow[f] * w;
            s2p += w * w;
        }
        for (int off = 32; off; off >>= 1) {
            pr += __shfl_down(pr, off, 64);
            s2p += __shfl_down(s2p, off, 64);
        }
        s2p = __shfl(s2p, 0, 64);
        if (lane == 0) score[node] = tanhf(pr / sqrtf(s2p));
    }
}

// ---------------------------------------------------------------------------
__global__ __launch_bounds__(256)
void topk_cur(const float* __restrict__ score, int npg, int k,
              int* __restrict__ kept, int* __restrict__ cur) {
    __shared__ float ss[256];
    __shared__ int si_[256];
    __shared__ int rankOf[256];
    const int g = blockIdx.x;
    const int t = threadIdx.x;
    if (t < npg) { ss[t] = score[g * npg + t]; si_[t] = t; }
    else         { ss[t] = -INFINITY; si_[t] = 0x7FFFFFFF; }
    for (int size = 2; size <= 256; size <<= 1) {
        for (int stride = size >> 1; stride > 0; stride >>= 1) {
            __syncthreads();
            int i = t, j = t ^ stride;
            if (j > i) {
                float a = ss[i], b = ss[j];
                int ia = si_[i], ib = si_[j];
                bool inOrder = (a > b) || (a == b && ia < ib);
                bool desc = ((i & size) == 0);
                if (desc ? !inOrder : inOrder) {
                    ss[i] = b; ss[j] = a; si_[i] = ib; si_[j] = ia;
                }
            }
        }
    }
    __syncthreads();
    rankOf[t] = -1;
    __syncthreads();
    if (t < k) {
        kept[g * k + t] = g * npg + si_[t];
        rankOf[si_[t]] = t;
    }
    __syncthreads();
    {
        int v = g * 256 + t;
        int c = cur[v];
        cur[v] = (c >= 0) ? rankOf[c] : -1;
    }
}

__global__ __launch_bounds__(256)
void pool_gather(const int* __restrict__ kept, const float* __restrict__ score,
                 const float* __restrict__ H2, float* __restrict__ OUT) {
    const int j = blockIdx.x;
    const int t = threadIdx.x;
    const int o = kept[j];
    OUT[(size_t)j * 256 + t] = H2[(size_t)o * 256 + t] * score[o];
}

__global__ __launch_bounds__(256)
void readout(const float* __restrict__ X, int k, float* __restrict__ outacc,
             int first) {
    const int g = blockIdx.x;
    const int t = threadIdx.x;
    const float* base = X + (size_t)g * k * 256 + t;
    float mx = -INFINITY, sm = 0.f;
    for (int n = 0; n < k; ++n) {
        float vv = base[(size_t)n * 256];
        mx = fmaxf(mx, vv);
        sm += vv;
    }
    float mean = sm / (float)k;
    if (first) {
        outacc[g * 512 + t] = mx;
        outacc[g * 512 + 256 + t] = mean;
    } else {
        outacc[g * 512 + t] += mx;
        outacc[g * 512 + 256 + t] += mean;
    }
}

__global__ __launch_bounds__(256)
void mlp_head(const float* __restrict__ outacc,
              const float* __restrict__ l1w, const float* __restrict__ l1b,
              const float* __restrict__ l2w, const float* __restrict__ l2b,
              const float* __restrict__ l3w, const float* __restrict__ l3b,
              float* __restrict__ out) {
    __shared__ float row[512];
    __shared__ float h1[256];
    __shared__ float h2[128];
    const int g = blockIdx.x;
    const int t = threadIdx.x;
    row[t] = outacc[g * 512 + t];
    row[256 + t] = outacc[g * 512 + 256 + t];
    __syncthreads();
    {
        float a = l1b[t];
        for (int j = 0; j < 512; ++j) a += row[j] * l1w[j * 256 + t];
        h1[t] = fmaxf(a, 0.f);
    }
    __syncthreads();
    if (t < 128) {
        float a2 = l2b[t];
        for (int j = 0; j < 256; ++j) a2 += h1[j] * l2w[j * 128 + t];
        h2[t] = fmaxf(a2, 0.f);
    }
    __syncthreads();
    if (t == 0) {
        float l0 = l3b[0], l1 = l3b[1];
        for (int j = 0; j < 128; ++j) {
            float h = h2[j];
            l0 += h * l3w[j * 2 + 0];
            l1 += h * l3w[j * 2 + 1];
        }
        float m = fmaxf(l0, l1);
        float lse = m + logf(expf(l0 - m) + expf(l1 - m));
        out[g * 2 + 0] = l0 - lse;
        out[g * 2 + 1] = l1 - lse;
    }
}

// ============================================================================
// Fallback: proven R15 monolith (used only if ws_size is too small)
// ============================================================================
__global__ __launch_bounds__(256, 1)
void gnn_mono(const float* __restrict__ x, const int* __restrict__ ei,
              const float* __restrict__ gw0, const float* __restrict__ gb0,
              const float* __restrict__ gw1, const float* __restrict__ gb1,
              const float* __restrict__ gw2, const float* __restrict__ gb2,
              const float* __restrict__ pw0, const float* __restrict__ pw1,
              const float* __restrict__ pw2,
              const float* __restrict__ l1w, const float* __restrict__ l1b,
              const float* __restrict__ l2w, const float* __restrict__ l2b,
              const float* __restrict__ l3w, const float* __restrict__ l3b,
              float* __restrict__ out, float* __restrict__ ws) {
    const int g = blockIdx.x;
    const int t = threadIdx.x;
    float* P = ws + (size_t)g * HF * 256;
    float* Q = ws + (size_t)G_GRAPHS * HF * 256 + (size_t)g * HF * 256;
    __shared__ int   eb[EPG];
    __shared__ int   slots[EPG];
    __shared__ int   curID[256];
    __shared__ int   cntL[256];
    __shared__ int   startL[256];
    __shared__ float degF[256];
    __shared__ float dinv[256];
    __shared__ float sa[256];
    __shared__ float ss[256];
    __shared__ int   si_[256];
    __shared__ float scoreV[256];
    __shared__ int   kept[128];
    __shared__ int   rankOf[256];
    __shared__ float row[512];
    for (int e = t; e < EPG; e += 256) {
        size_t idx = (size_t)g * EPG + e;
        eb[e] = ((ei[idx] - g * 256) << 8) | (ei[E_TOT + idx] - g * 256);
    }
    curID[t] = t;
    float accMx = 0.f, accMn = 0.f;
    const float* GW[3] = {gw0, gw1, gw2};
    const float* GB[3] = {gb0, gb1, gb2};
    const float* PW[3] = {pw0, pw1, pw2};
    const int kk[3] = {128, 64, 32};
    int npg = 256;
    __syncthreads();
    for (int s = 0; s < 3; ++s) {
        const int knext = kk[s];
        {
            const float* Wp = GW[s];
            const int K = (s == 0) ? FIN : HF;
            for (int n = 0; n < npg; ++n) {
                if (s == 0) { if (t < FIN) sa[t] = x[(size_t)(g * 256 + n) * FIN + t]; }
                else sa[t] = P[(size_t)n * HF + t];
                __syncthreads();
                float a = 0.f;
                for (int k2 = 0; k2 < K; ++k2) a += sa[k2] * Wp[k2 * HF + t];
                Q[(size_t)n * HF + t] = a;
                __syncthreads();
            }
        }
        cntL[t] = 0;
        __syncthreads();
        for (int e = t; e < EPG; e += 256) {
            int p = eb[e];
            int cu = curID[p >> 8], cv = curID[p & 255];
            if (cu >= 0 && cv >= 0) atomicAdd(&cntL[cv], 1);
        }
        __syncthreads();
        if (t == 0) { int run = 0; for (int i = 0; i < npg; ++i) { startL[i] = run; run += cntL[i]; } }
        __syncthreads();
        if (t < npg) {
            float d = (float)cntL[t] + 1.0f;
            degF[t] = d;
            dinv[t] = 1.0f / sqrtf(d);
            int c = startL[t];
            for (int e = 0; e < EPG; ++e) {
                int p = eb[e];
                int cu = curID[p >> 8], cv = curID[p & 255];
                if (cu >= 0 && cv >= 0 && cv == t) slots[c++] = e;
            }
        }
        __syncthreads();
        {
            const float bb = GB[s][t];
            for (int n = 0; n < npg; ++n) {
                float acc = 0.f;
                const int s0 = startL[n], s1 = s0 + cntL[n];
                for (int j = s0; j < s1; ++j) {
                    int scur = curID[eb[slots[j]] >> 8];
                    acc += dinv[scur] * Q[(size_t)scur * HF + t];
                }
                float v = acc * dinv[n] + Q[(size_t)n * HF + t] / degF[n] + bb;
                P[(size_t)n * HF + t] = fmaxf(v, 0.f);
            }
        }
        __syncthreads();
        {
            const float* pwp = PW[s];
            const int lane = t & 63, wv = t >> 6;
            float s2p = 0.f;
            for (int j = 0; j < 4; ++j) { float w = pwp[lane + 64 * j]; s2p += w * w; }
            for (int off = 32; off; off >>= 1) s2p += __shfl_down(s2p, off, 64);
            s2p = __shfl(s2p, 0, 64);
            const float nw = sqrtf(s2p);
            for (int n = wv; n < npg; n += 4) {
                float pr = 0.f;
                for (int j = 0; j < 4; ++j) { int f = lane + 64 * j; pr += P[(size_t)n * HF + f] * pwp[f]; }
                for (int off = 32; off; off >>= 1) pr += __shfl_down(pr, off, 64);
                if (lane == 0) scoreV[n] = tanhf(pr / nw);
            }
        }
        __syncthreads();
        if (t < npg) { ss[t] = scoreV[t]; si_[t] = t; }
        else         { ss[t] = -INFINITY; si_[t] = 0x7FFFFFFF; }
        for (int size = 2; size <= 256; size <<= 1) {
            for (int stride = size >> 1; stride > 0; stride >>= 1) {
                __syncthreads();
                int i = t, j = t ^ stride;
                if (j > i) {
                    float a = ss[i], b = ss[j];
                    int ia = si_[i], ib = si_[j];
                    bool inOrder = (a > b) || (a == b && ia < ib);
                    bool desc = ((i & size) == 0);
                    if (desc ? !inOrder : inOrder) { ss[i] = b; ss[j] = a; si_[i] = ib; si_[j] = ia; }
                }
            }
        }
        __syncthreads();
        if (t < knext) kept[t] = si_[t];
        __syncthreads();
        {
            float mx = -INFINITY, sm = 0.f;
            for (int n = 0; n < knext; ++n) {
                int o = kept[n];
                float vv = P[(size_t)o * HF + t] * scoreV[o];
                Q[(size_t)n * HF + t] = vv;
                mx = fmaxf(mx, vv);
                sm += vv;
            }
            accMx += mx;
            accMn += sm / (float)knext;
        }
        rankOf[t] = -1;
        __syncthreads();
        if (t < knext) rankOf[kept[t]] = t;
        __syncthreads();
        { int c = curID[t]; curID[t] = (c >= 0) ? rankOf[c] : -1; }
        __syncthreads();
        { float* tmp = P; P = Q; Q = tmp; }
        npg = knext;
    }
    row[t] = accMx;
    row[256 + t] = accMn;
    __syncthreads();
    { float a = l1b[t]; for (int j = 0; j < 512; ++j) a += row[j] * l1w[j * 256 + t]; scoreV[t] = fmaxf(a, 0.f); }
    __syncthreads();
    if (t < 128) { float a2 = l2b[t]; for (int j = 0; j < 256; ++j) a2 += scoreV[j] * l2w[j * 128 + t]; sa[t] = fmaxf(a2, 0.f); }
    __syncthreads();
    if (t == 0) {
        float l0 = l3b[0], l1 = l3b[1];
        for (int j = 0; j < 128; ++j) { float h = sa[j]; l0 += h * l3w[j * 2 + 0]; l1 += h * l3w[j * 2 + 1]; }
        float m = fmaxf(l0, l1);
        float lse = m + logf(expf(l0 - m) + expf(l1 - m));
        out[g * 2 + 0] = l0 - lse;
        out[g * 2 + 1] = l1 - lse;
    }
}

// ============================================================================
extern "C" void kernel_launch(void* const* d_in, const int* in_sizes, int n_in,
                              void* d_out, int out_size, void* d_ws, size_t ws_size,
                              hipStream_t stream) {
    const float* x   = (const float*)d_in[0];
    const int*   ei  = (const int*)d_in[1];
    const float* gw0 = (const float*)d_in[3];
    const float* gb0 = (const float*)d_in[4];
    const float* gw1 = (const float*)d_in[5];
    const float* gb1 = (const float*)d_in[6];
    const float* gw2 = (const float*)d_in[7];
    const float* gb2 = (const float*)d_in[8];
    const float* pw0 = (const float*)d_in[9];
    const float* pw1 = (const float*)d_in[10];
    const float* pw2 = (const float*)d_in[11];
    const float* l1w = (const float*)d_in[12];
    const float* l1b = (const float*)d_in[13];
    const float* l2w = (const float*)d_in[14];
    const float* l2b = (const float*)d_in[15];
    const float* l3w = (const float*)d_in[16];
    const float* l3b = (const float*)d_in[17];
    float* out = (float*)d_out;

    const size_t SLAB = (size_t)65536 * 256;
    char* p = (char*)d_ws;
    float* P      = (float*)p; p += SLAB * 4;
    float* Q      = (float*)p; p += SLAB * 4;
    int*   cur    = (int*)p;   p += (size_t)65536 * 4;
    int*   degS   = (int*)p;   p += (size_t)65536 * 4;
    float* dinvS  = (float*)p; p += (size_t)65536 * 4;
    int*   starts = (int*)p;   p += (size_t)65536 * 4;
    int*   slotsS = (int*)p;   p += (size_t)E_TOT * 4;
    float* score  = (float*)p; p += (size_t)65536 * 4;
    int*   kept   = (int*)p;   p += (size_t)32768 * 4;
    float* outacc = (float*)p; p += (size_t)G_GRAPHS * 512 * 4;
    const size_t needed = (size_t)(p - (char*)d_ws);

    if (ws_size < needed) {
        gnn_mono<<<G_GRAPHS, 256, 0, stream>>>(
            x, ei, gw0, gb0, gw1, gb1, gw2, gb2, pw0, pw1, pw2,
            l1w, l1b, l2w, l2b, l3w, l3b, out, (float*)d_ws);
        return;
    }

    init_cur<<<(G_GRAPHS * 256 + 255) / 256, 256, 0, stream>>>(cur);

    const int   npg[3] = {256, 128, 64};
    const int   kk[3]  = {128, 64, 32};
    const int   Ns[3]  = {65536, 32768, 16384};
    const float* GW[3] = {gw0, gw1, gw2};
    const float* GB[3] = {gb0, gb1, gb2};
    const float* PW[3] = {pw0, pw1, pw2};

    float* HLs[3]   = {P, Q, P};
    float* H2s[3]   = {Q, P, Q};
    float* POOLs[3] = {P, Q, P};

    for (int s = 0; s < 3; ++s) {
        const int n = Ns[s];
        const int k = kk[s];
        // 1) GEMM
        if (s == 0) {
            dim3 grid(n / 64, 4);
            gemm_t4<FIN><<<grid, 256, 0, stream>>>(x, GW[s], HLs[s]);
        } else {
            dim3 grid(n / 64, 4);
            gemm_t4<HF><<<grid, 256, 0, stream>>>(POOLs[s - 1], GW[s], HLs[s]);
        }
        // 2) CSR
        csr_build<<<G_GRAPHS, 256, 0, stream>>>(ei, cur, npg[s],
                                                degS, dinvS, starts, slotsS);
        // 3) conv + score (XCD-swizzled node mapping)
        agg_score<<<n, 256, 0, stream>>>(degS, dinvS, starts, slotsS,
                                         HLs[s], H2s[s], GB[s], PW[s], score,
                                         n / 8);
        // 4) top-k + cur update
        topk_cur<<<G_GRAPHS, 256, 0, stream>>>(score, npg[s], k, kept, cur);
        // 5) pool
        pool_gather<<<G_GRAPHS * k, 256, 0, stream>>>(kept, score, H2s[s], POOLs[s]);
        // 6) readout
        readout<<<G_GRAPHS, 256, 0, stream>>>(POOLs[s], k, outacc, s == 0 ? 1 : 0);
    }

    mlp_head<<<G_GRAPHS, 256, 0, stream>>>(outacc, l1w, l1b, l2w, l2b, l3w, l3b, out);
}

// Round 19
// 665.617 us; speedup vs baseline: 1.7690x; 1.4711x over previous
//
#include <hip/hip_runtime.h>
#include <hip/hip_bf16.h>
#include <math.h>

#define G_GRAPHS 256
#define EPG 2048
#define E_TOT 524288
#define HF 256
#define FIN 128

// ============================================================================
__global__ void init_cur(int* __restrict__ cur) {
    int i = blockIdx.x * blockDim.x + threadIdx.x;
    if (i < G_GRAPHS * 256) cur[i] = i & 255;
}

// ---------------------------------------------------------------------------
// C[N x 256] = A[N x K] @ W[K x 256], fp32, k-ascending accumulation.
// ---------------------------------------------------------------------------
template <int K>
__global__ __launch_bounds__(256)
void gemm_t4(const float* __restrict__ A, const float* __restrict__ W,
             float* __restrict__ C) {
    __shared__ float As[64][68];
    __shared__ float Ws[64][68];
    const int tid = threadIdx.x;
    const int tx = tid & 15;
    const int ty = tid >> 4;
    const int r0 = blockIdx.x * 64;
    const int c0 = blockIdx.y * 64;
    float acc[4][4] = {{0.f}};
    for (int k0 = 0; k0 < K; k0 += 64) {
        for (int i = tid; i < 4096; i += 256) {
            int r = i >> 6, kk = i & 63;
            As[kk][r] = A[(size_t)(r0 + r) * K + (k0 + kk)];
        }
        for (int i = tid; i < 4096; i += 256) {
            int kk = i >> 6, c = i & 63;
            Ws[kk][c] = W[(size_t)(k0 + kk) * 256 + (c0 + c)];
        }
        __syncthreads();
#pragma unroll 8
        for (int kk = 0; kk < 64; ++kk) {
            float4 av = *(const float4*)&As[kk][ty * 4];
            float4 wv = *(const float4*)&Ws[kk][tx * 4];
            acc[0][0] += av.x * wv.x; acc[0][1] += av.x * wv.y;
            acc[0][2] += av.x * wv.z; acc[0][3] += av.x * wv.w;
            acc[1][0] += av.y * wv.x; acc[1][1] += av.y * wv.y;
            acc[1][2] += av.y * wv.z; acc[1][3] += av.y * wv.w;
            acc[2][0] += av.z * wv.x; acc[2][1] += av.z * wv.y;
            acc[2][2] += av.z * wv.z; acc[2][3] += av.z * wv.w;
            acc[3][0] += av.w * wv.x; acc[3][1] += av.w * wv.y;
            acc[3][2] += av.w * wv.z; acc[3][3] += av.w * wv.w;
        }
        __syncthreads();
    }
#pragma unroll
    for (int i = 0; i < 4; ++i) {
        float4 v = make_float4(acc[i][0], acc[i][1], acc[i][2], acc[i][3]);
        *(float4*)&C[(size_t)(r0 + ty * 4 + i) * 256 + c0 + tx * 4] = v;
    }
}

// ---------------------------------------------------------------------------
// Parallel STABLE counting-sort CSR (slots in ascending edge order per dst —
// bit-identical to the serial build). Within-chunk stable rank via 9-bit
// ballot match (invalid dst = 256); per-chunk histograms + per-dst scan.
// ---------------------------------------------------------------------------
__global__ __launch_bounds__(256)
void csr_build(const int* __restrict__ ei, const int* __restrict__ cur, int npg,
               int* __restrict__ degS, float* __restrict__ dinvS,
               int* __restrict__ startsS, int* __restrict__ slotsS) {
    __shared__ int cul[EPG];            // src current local id
    __shared__ short dstv[EPG];         // dst current local id, 256 if invalid
    __shared__ unsigned char rnk[EPG];  // within-chunk stable rank
    __shared__ int h[32][256];          // per-chunk count -> exclusive base
    __shared__ int cnt[256];
    __shared__ int st[256];
    const int g = blockIdx.x;
    const int t = threadIdx.x;
    const int lane = t & 63;
    const int wv = t >> 6;

    for (int i = t; i < 32 * 256; i += 256) ((int*)h)[i] = 0;
    for (int e = t; e < EPG; e += 256) {
        size_t idx = (size_t)g * EPG + e;
        int cu = cur[g * 256 + (ei[idx] - g * 256)];
        int cv = cur[g * 256 + (ei[E_TOT + idx] - g * 256)];
        bool valid = (cu >= 0 && cv >= 0);
        cul[e] = cu;
        dstv[e] = valid ? (short)cv : (short)256;
    }
    __syncthreads();

    // Phase A: per 64-edge chunk (one wave each): stable rank + group counts
    for (int c = wv; c < 32; c += 4) {
        int e = c * 64 + lane;
        int d = (int)dstv[e];
        unsigned long long m = ~0ULL;
#pragma unroll
        for (int b = 0; b < 9; ++b) {
            unsigned long long bb = __ballot((d >> b) & 1);
            m &= ((d >> b) & 1) ? bb : ~bb;
        }
        int r = __popcll(m & ((1ULL << lane) - 1ULL));
        rnk[e] = (unsigned char)r;
        if (r == 0 && d < 256) h[c][d] = __popcll(m);
    }
    __syncthreads();

    // Phase B: per-dst exclusive scan over chunks; deg/dinv
    if (t < npg) {
        int run = 0;
        for (int c = 0; c < 32; ++c) { int v = h[c][t]; h[c][t] = run; run += v; }
        cnt[t] = run;
        degS[g * npg + t] = run + 1;
        dinvS[g * npg + t] = 1.0f / sqrtf((float)(run + 1));
    }
    __syncthreads();
    if (t == 0) {
        int run = 0;
        for (int i = 0; i < npg; ++i) { st[i] = run; run += cnt[i]; }
    }
    __syncthreads();
    if (t < npg) startsS[g * npg + t] = g * EPG + st[t];

    // Phase C: fully parallel stable placement
    for (int e = t; e < EPG; e += 256) {
        int d = (int)dstv[e];
        if (d < npg) {
            int slot = st[d] + h[e >> 6][d] + (int)rnk[e];
            slotsS[g * EPG + slot] = g * npg + cul[e];
        }
    }
}

// ---------------------------------------------------------------------------
// conv + relu + pool score with XCD-locality swizzle (R18-proven).
// ---------------------------------------------------------------------------
__global__ __launch_bounds__(256)
void agg_score(const int* __restrict__ degS, const float* __restrict__ dinvS,
               const int* __restrict__ startsS, const int* __restrict__ slotsS,
               const float* __restrict__ HL, float* __restrict__ H2,
               const float* __restrict__ bias, const float* __restrict__ pw,
               float* __restrict__ score, int nOver8) {
    __shared__ float vrow[256];
    const int node = (blockIdx.x & 7) * nOver8 + (blockIdx.x >> 3);
    const int t = threadIdx.x;
    const int cntE = degS[node] - 1;
    const float degF = (float)degS[node];
    const float dn = dinvS[node];
    const int s0 = startsS[node];
    float acc = 0.f;
    for (int j = 0; j < cntE; ++j) {
        int srcg = slotsS[s0 + j];
        acc += dinvS[srcg] * HL[(size_t)srcg * 256 + t];
    }
    float v = acc * dn + HL[(size_t)node * 256 + t] / degF + bias[t];
    v = fmaxf(v, 0.f);
    H2[(size_t)node * 256 + t] = v;
    vrow[t] = v;
    __syncthreads();
    if (t < 64) {
        const int lane = t;
        float pr = 0.f, s2p = 0.f;
        for (int j = 0; j < 4; ++j) {
            int f = lane + 64 * j;
            float w = pw[f];
            pr += vrow[f] * w;
            s2p += w * w;
        }
        for (int off = 32; off; off >>= 1) {
            pr += __shfl_down(pr, off, 64);
            s2p += __shfl_down(s2p, off, 64);
        }
        s2p = __shfl(s2p, 0, 64);
        if (lane == 0) score[node] = tanhf(pr / sqrtf(s2p));
    }
}

// ---------------------------------------------------------------------------
__global__ __launch_bounds__(256)
void topk_cur(const float* __restrict__ score, int npg, int k,
              int* __restrict__ kept, int* __restrict__ cur) {
    __shared__ float ss[256];
    __shared__ int si_[256];
    __shared__ int rankOf[256];
    const int g = blockIdx.x;
    const int t = threadIdx.x;
    if (t < npg) { ss[t] = score[g * npg + t]; si_[t] = t; }
    else         { ss[t] = -INFINITY; si_[t] = 0x7FFFFFFF; }
    for (int size = 2; size <= 256; size <<= 1) {
        for (int stride = size >> 1; stride > 0; stride >>= 1) {
            __syncthreads();
            int i = t, j = t ^ stride;
            if (j > i) {
                float a = ss[i], b = ss[j];
                int ia = si_[i], ib = si_[j];
                bool inOrder = (a > b) || (a == b && ia < ib);
                bool desc = ((i & size) == 0);
                if (desc ? !inOrder : inOrder) {
                    ss[i] = b; ss[j] = a; si_[i] = ib; si_[j] = ia;
                }
            }
        }
    }
    __syncthreads();
    rankOf[t] = -1;
    __syncthreads();
    if (t < k) {
        kept[g * k + t] = g * npg + si_[t];
        rankOf[si_[t]] = t;
    }
    __syncthreads();
    {
        int v = g * 256 + t;
        int c = cur[v];
        cur[v] = (c >= 0) ? rankOf[c] : -1;
    }
}

__global__ __launch_bounds__(256)
void pool_gather(const int* __restrict__ kept, const float* __restrict__ score,
                 const float* __restrict__ H2, float* __restrict__ OUT) {
    const int j = blockIdx.x;
    const int t = threadIdx.x;
    const int o = kept[j];
    OUT[(size_t)j * 256 + t] = H2[(size_t)o * 256 + t] * score[o];
}

__global__ __launch_bounds__(256)
void readout(const float* __restrict__ X, int k, float* __restrict__ outacc,
             int first) {
    const int g = blockIdx.x;
    const int t = threadIdx.x;
    const float* base = X + (size_t)g * k * 256 + t;
    float mx = -INFINITY, sm = 0.f;
    for (int n = 0; n < k; ++n) {
        float vv = base[(size_t)n * 256];
        mx = fmaxf(mx, vv);
        sm += vv;
    }
    float mean = sm / (float)k;
    if (first) {
        outacc[g * 512 + t] = mx;
        outacc[g * 512 + 256 + t] = mean;
    } else {
        outacc[g * 512 + t] += mx;
        outacc[g * 512 + 256 + t] += mean;
    }
}

__global__ __launch_bounds__(256)
void mlp_head(const float* __restrict__ outacc,
              const float* __restrict__ l1w, const float* __restrict__ l1b,
              const float* __restrict__ l2w, const float* __restrict__ l2b,
              const float* __restrict__ l3w, const float* __restrict__ l3b,
              float* __restrict__ out) {
    __shared__ float row[512];
    __shared__ float h1[256];
    __shared__ float h2[128];
    const int g = blockIdx.x;
    const int t = threadIdx.x;
    row[t] = outacc[g * 512 + t];
    row[256 + t] = outacc[g * 512 + 256 + t];
    __syncthreads();
    {
        float a = l1b[t];
        for (int j = 0; j < 512; ++j) a += row[j] * l1w[j * 256 + t];
        h1[t] = fmaxf(a, 0.f);
    }
    __syncthreads();
    if (t < 128) {
        float a2 = l2b[t];
        for (int j = 0; j < 256; ++j) a2 += h1[j] * l2w[j * 128 + t];
        h2[t] = fmaxf(a2, 0.f);
    }
    __syncthreads();
    if (t == 0) {
        float l0 = l3b[0], l1 = l3b[1];
        for (int j = 0; j < 128; ++j) {
            float h = h2[j];
            l0 += h * l3w[j * 2 + 0];
            l1 += h * l3w[j * 2 + 1];
        }
        float m = fmaxf(l0, l1);
        float lse = m + logf(expf(l0 - m) + expf(l1 - m));
        out[g * 2 + 0] = l0 - lse;
        out[g * 2 + 1] = l1 - lse;
    }
}

// ============================================================================
// Fallback: proven R15 monolith (used only if ws_size is too small)
// ============================================================================
__global__ __launch_bounds__(256, 1)
void gnn_mono(const float* __restrict__ x, const int* __restrict__ ei,
              const float* __restrict__ gw0, const float* __restrict__ gb0,
              const float* __restrict__ gw1, const float* __restrict__ gb1,
              const float* __restrict__ gw2, const float* __restrict__ gb2,
              const float* __restrict__ pw0, const float* __restrict__ pw1,
              const float* __restrict__ pw2,
              const float* __restrict__ l1w, const float* __restrict__ l1b,
              const float* __restrict__ l2w, const float* __restrict__ l2b,
              const float* __restrict__ l3w, const float* __restrict__ l3b,
              float* __restrict__ out, float* __restrict__ ws) {
    const int g = blockIdx.x;
    const int t = threadIdx.x;
    float* P = ws + (size_t)g * HF * 256;
    float* Q = ws + (size_t)G_GRAPHS * HF * 256 + (size_t)g * HF * 256;
    __shared__ int   eb[EPG];
    __shared__ int   slots[EPG];
    __shared__ int   curID[256];
    __shared__ int   cntL[256];
    __shared__ int   startL[256];
    __shared__ float degF[256];
    __shared__ float dinv[256];
    __shared__ float sa[256];
    __shared__ float ss[256];
    __shared__ int   si_[256];
    __shared__ float scoreV[256];
    __shared__ int   kept[128];
    __shared__ int   rankOf[256];
    __shared__ float row[512];
    for (int e = t; e < EPG; e += 256) {
        size_t idx = (size_t)g * EPG + e;
        eb[e] = ((ei[idx] - g * 256) << 8) | (ei[E_TOT + idx] - g * 256);
    }
    curID[t] = t;
    float accMx = 0.f, accMn = 0.f;
    const float* GW[3] = {gw0, gw1, gw2};
    const float* GB[3] = {gb0, gb1, gb2};
    const float* PW[3] = {pw0, pw1, pw2};
    const int kk[3] = {128, 64, 32};
    int npg = 256;
    __syncthreads();
    for (int s = 0; s < 3; ++s) {
        const int knext = kk[s];
        {
            const float* Wp = GW[s];
            const int K = (s == 0) ? FIN : HF;
            for (int n = 0; n < npg; ++n) {
                if (s == 0) { if (t < FIN) sa[t] = x[(size_t)(g * 256 + n) * FIN + t]; }
                else sa[t] = P[(size_t)n * HF + t];
                __syncthreads();
                float a = 0.f;
                for (int k2 = 0; k2 < K; ++k2) a += sa[k2] * Wp[k2 * HF + t];
                Q[(size_t)n * HF + t] = a;
                __syncthreads();
            }
        }
        cntL[t] = 0;
        __syncthreads();
        for (int e = t; e < EPG; e += 256) {
            int p = eb[e];
            int cu = curID[p >> 8], cv = curID[p & 255];
            if (cu >= 0 && cv >= 0) atomicAdd(&cntL[cv], 1);
        }
        __syncthreads();
        if (t == 0) { int run = 0; for (int i = 0; i < npg; ++i) { startL[i] = run; run += cntL[i]; } }
        __syncthreads();
        if (t < npg) {
            float d = (float)cntL[t] + 1.0f;
            degF[t] = d;
            dinv[t] = 1.0f / sqrtf(d);
            int c = startL[t];
            for (int e = 0; e < EPG; ++e) {
                int p = eb[e];
                int cu = curID[p >> 8], cv = curID[p & 255];
                if (cu >= 0 && cv >= 0 && cv == t) slots[c++] = e;
            }
        }
        __syncthreads();
        {
            const float bb = GB[s][t];
            for (int n = 0; n < npg; ++n) {
                float acc = 0.f;
                const int s0 = startL[n], s1 = s0 + cntL[n];
                for (int j = s0; j < s1; ++j) {
                    int scur = curID[eb[slots[j]] >> 8];
                    acc += dinv[scur] * Q[(size_t)scur * HF + t];
                }
                float v = acc * dinv[n] + Q[(size_t)n * HF + t] / degF[n] + bb;
                P[(size_t)n * HF + t] = fmaxf(v, 0.f);
            }
        }
        __syncthreads();
        {
            const float* pwp = PW[s];
            const int lane = t & 63, wv = t >> 6;
            float s2p = 0.f;
            for (int j = 0; j < 4; ++j) { float w = pwp[lane + 64 * j]; s2p += w * w; }
            for (int off = 32; off; off >>= 1) s2p += __shfl_down(s2p, off, 64);
            s2p = __shfl(s2p, 0, 64);
            const float nw = sqrtf(s2p);
            for (int n = wv; n < npg; n += 4) {
                float pr = 0.f;
                for (int j = 0; j < 4; ++j) { int f = lane + 64 * j; pr += P[(size_t)n * HF + f] * pwp[f]; }
                for (int off = 32; off; off >>= 1) pr += __shfl_down(pr, off, 64);
                if (lane == 0) scoreV[n] = tanhf(pr / nw);
            }
        }
        __syncthreads();
        if (t < npg) { ss[t] = scoreV[t]; si_[t] = t; }
        else         { ss[t] = -INFINITY; si_[t] = 0x7FFFFFFF; }
        for (int size = 2; size <= 256; size <<= 1) {
            for (int stride = size >> 1; stride > 0; stride >>= 1) {
                __syncthreads();
                int i = t, j = t ^ stride;
                if (j > i) {
                    float a = ss[i], b = ss[j];
                    int ia = si_[i], ib = si_[j];
                    bool inOrder = (a > b) || (a == b && ia < ib);
                    bool desc = ((i & size) == 0);
                    if (desc ? !inOrder : inOrder) { ss[i] = b; ss[j] = a; si_[i] = ib; si_[j] = ia; }
                }
            }
        }
        __syncthreads();
        if (t < knext) kept[t] = si_[t];
        __syncthreads();
        {
            float mx = -INFINITY, sm = 0.f;
            for (int n = 0; n < knext; ++n) {
                int o = kept[n];
                float vv = P[(size_t)o * HF + t] * scoreV[o];
                Q[(size_t)n * HF + t] = vv;
                mx = fmaxf(mx, vv);
                sm += vv;
            }
            accMx += mx;
            accMn += sm / (float)knext;
        }
        rankOf[t] = -1;
        __syncthreads();
        if (t < knext) rankOf[kept[t]] = t;
        __syncthreads();
        { int c = curID[t]; curID[t] = (c >= 0) ? rankOf[c] : -1; }
        __syncthreads();
        { float* tmp = P; P = Q; Q = tmp; }
        npg = knext;
    }
    row[t] = accMx;
    row[256 + t] = accMn;
    __syncthreads();
    { float a = l1b[t]; for (int j = 0; j < 512; ++j) a += row[j] * l1w[j * 256 + t]; scoreV[t] = fmaxf(a, 0.f); }
    __syncthreads();
    if (t < 128) { float a2 = l2b[t]; for (int j = 0; j < 256; ++j) a2 += scoreV[j] * l2w[j * 128 + t]; sa[t] = fmaxf(a2, 0.f); }
    __syncthreads();
    if (t == 0) {
        float l0 = l3b[0], l1 = l3b[1];
        for (int j = 0; j < 128; ++j) { float h = sa[j]; l0 += h * l3w[j * 2 + 0]; l1 += h * l3w[j * 2 + 1]; }
        float m = fmaxf(l0, l1);
        float lse = m + logf(expf(l0 - m) + expf(l1 - m));
        out[g * 2 + 0] = l0 - lse;
        out[g * 2 + 1] = l1 - lse;
    }
}

// ============================================================================
extern "C" void kernel_launch(void* const* d_in, const int* in_sizes, int n_in,
                              void* d_out, int out_size, void* d_ws, size_t ws_size,
                              hipStream_t stream) {
    const float* x   = (const float*)d_in[0];
    const int*   ei  = (const int*)d_in[1];
    const float* gw0 = (const float*)d_in[3];
    const float* gb0 = (const float*)d_in[4];
    const float* gw1 = (const float*)d_in[5];
    const float* gb1 = (const float*)d_in[6];
    const float* gw2 = (const float*)d_in[7];
    const float* gb2 = (const float*)d_in[8];
    const float* pw0 = (const float*)d_in[9];
    const float* pw1 = (const float*)d_in[10];
    const float* pw2 = (const float*)d_in[11];
    const float* l1w = (const float*)d_in[12];
    const float* l1b = (const float*)d_in[13];
    const float* l2w = (const float*)d_in[14];
    const float* l2b = (const float*)d_in[15];
    const float* l3w = (const float*)d_in[16];
    const float* l3b = (const float*)d_in[17];
    float* out = (float*)d_out;

    const size_t SLAB = (size_t)65536 * 256;
    char* p = (char*)d_ws;
    float* P      = (float*)p; p += SLAB * 4;
    float* Q      = (float*)p; p += SLAB * 4;
    int*   cur    = (int*)p;   p += (size_t)65536 * 4;
    int*   degS   = (int*)p;   p += (size_t)65536 * 4;
    float* dinvS  = (float*)p; p += (size_t)65536 * 4;
    int*   starts = (int*)p;   p += (size_t)65536 * 4;
    int*   slotsS = (int*)p;   p += (size_t)E_TOT * 4;
    float* score  = (float*)p; p += (size_t)65536 * 4;
    int*   kept   = (int*)p;   p += (size_t)32768 * 4;
    float* outacc = (float*)p; p += (size_t)G_GRAPHS * 512 * 4;
    const size_t needed = (size_t)(p - (char*)d_ws);

    if (ws_size < needed) {
        gnn_mono<<<G_GRAPHS, 256, 0, stream>>>(
            x, ei, gw0, gb0, gw1, gb1, gw2, gb2, pw0, pw1, pw2,
            l1w, l1b, l2w, l2b, l3w, l3b, out, (float*)d_ws);
        return;
    }

    init_cur<<<(G_GRAPHS * 256 + 255) / 256, 256, 0, stream>>>(cur);

    const int   npg[3] = {256, 128, 64};
    const int   kk[3]  = {128, 64, 32};
    const int   Ns[3]  = {65536, 32768, 16384};
    const float* GW[3] = {gw0, gw1, gw2};
    const float* GB[3] = {gb0, gb1, gb2};
    const float* PW[3] = {pw0, pw1, pw2};

    float* HLs[3]   = {P, Q, P};
    float* H2s[3]   = {Q, P, Q};
    float* POOLs[3] = {P, Q, P};

    for (int s = 0; s < 3; ++s) {
        const int n = Ns[s];
        const int k = kk[s];
        // 1) GEMM
        if (s == 0) {
            dim3 grid(n / 64, 4);
            gemm_t4<FIN><<<grid, 256, 0, stream>>>(x, GW[s], HLs[s]);
        } else {
            dim3 grid(n / 64, 4);
            gemm_t4<HF><<<grid, 256, 0, stream>>>(POOLs[s - 1], GW[s], HLs[s]);
        }
        // 2) CSR (parallel stable counting sort)
        csr_build<<<G_GRAPHS, 256, 0, stream>>>(ei, cur, npg[s],
                                                degS, dinvS, starts, slotsS);
        // 3) conv + score (XCD-swizzled node mapping)
        agg_score<<<n, 256, 0, stream>>>(degS, dinvS, starts, slotsS,
                                         HLs[s], H2s[s], GB[s], PW[s], score,
                                         n / 8);
        // 4) top-k + cur update
        topk_cur<<<G_GRAPHS, 256, 0, stream>>>(score, npg[s], k, kept, cur);
        // 5) pool
        pool_gather<<<G_GRAPHS * k, 256, 0, stream>>>(kept, score, H2s[s], POOLs[s]);
        // 6) readout
        readout<<<G_GRAPHS, 256, 0, stream>>>(POOLs[s], k, outacc, s == 0 ? 1 : 0);
    }

    mlp_head<<<G_GRAPHS, 256, 0, stream>>>(outacc, l1w, l1b, l2w, l2b, l3w, l3b, out);
}

// Round 20
// 603.955 us; speedup vs baseline: 1.9496x; 1.1021x over previous
//
#include <hip/hip_runtime.h>
#include <hip/hip_bf16.h>
#include <math.h>

#define G_GRAPHS 256
#define EPG 2048
#define E_TOT 524288
#define HF 256
#define FIN 128

// ============================================================================
__global__ void init_cur(int* __restrict__ cur) {
    int i = blockIdx.x * blockDim.x + threadIdx.x;
    if (i < G_GRAPHS * 256) cur[i] = i & 255;
}

// ---------------------------------------------------------------------------
// C[N x 256] = A[N x K] @ W[K x 256], fp32, k-ascending accumulation.
// Tile 64 rows x 128 cols, 4x8 per thread (tx=cols 0..15, ty=rows 0..15).
// A staged [row][65] (odd stride => conflict-free stores + reads);
// W staged [kk][136] (aligned float4; uniform-coverage stores, 2-way reads).
// ---------------------------------------------------------------------------
template <int K>
__global__ __launch_bounds__(256)
void gemm_v2(const float* __restrict__ A, const float* __restrict__ W,
             float* __restrict__ C) {
    __shared__ float As2[64 * 65];
    __shared__ float Ws[64 * 136];
    const int tid = threadIdx.x;
    const int tx = tid & 15;            // col group: 8 cols each
    const int ty = tid >> 4;            // row group: 4 rows each
    const int r0 = blockIdx.x * 64;
    const int c0 = blockIdx.y * 128;
    float acc[4][8] = {{0.f}};
    for (int k0 = 0; k0 < K; k0 += 64) {
        // stage A: 64 rows x 64 kk, float4 global loads, scalar LDS stores
        {
            int r = tid >> 4;           // 0..15 (+16 per it)
            int c = tid & 15;           // float4 index: kk = 4c
#pragma unroll
            for (int it = 0; it < 4; ++it) {
                float4 v = *(const float4*)&A[(size_t)(r0 + r) * K + k0 + 4 * c];
                float* dst = &As2[r * 65 + 4 * c];
                dst[0] = v.x; dst[1] = v.y; dst[2] = v.z; dst[3] = v.w;
                r += 16;
            }
        }
        // stage W: 64 kk x 128 cols, float4 both sides
        {
            int kk = tid >> 5;          // 0..7 (+8 per it)
            int c = tid & 31;           // float4 index: col = 4c
#pragma unroll
            for (int it = 0; it < 8; ++it) {
                float4 v = *(const float4*)&W[(size_t)(k0 + kk) * 256 + c0 + 4 * c];
                *(float4*)&Ws[kk * 136 + 4 * c] = v;
                kk += 8;
            }
        }
        __syncthreads();
#pragma unroll 4
        for (int kk = 0; kk < 64; ++kk) {
            float av0 = As2[(ty * 4 + 0) * 65 + kk];
            float av1 = As2[(ty * 4 + 1) * 65 + kk];
            float av2 = As2[(ty * 4 + 2) * 65 + kk];
            float av3 = As2[(ty * 4 + 3) * 65 + kk];
            float4 w0 = *(const float4*)&Ws[kk * 136 + tx * 8];
            float4 w1 = *(const float4*)&Ws[kk * 136 + tx * 8 + 4];
            float wv[8] = {w0.x, w0.y, w0.z, w0.w, w1.x, w1.y, w1.z, w1.w};
#pragma unroll
            for (int cc = 0; cc < 8; ++cc) {
                acc[0][cc] += av0 * wv[cc];
                acc[1][cc] += av1 * wv[cc];
                acc[2][cc] += av2 * wv[cc];
                acc[3][cc] += av3 * wv[cc];
            }
        }
        __syncthreads();
    }
#pragma unroll
    for (int i = 0; i < 4; ++i) {
        float4 v0 = make_float4(acc[i][0], acc[i][1], acc[i][2], acc[i][3]);
        float4 v1 = make_float4(acc[i][4], acc[i][5], acc[i][6], acc[i][7]);
        size_t base = (size_t)(r0 + ty * 4 + i) * 256 + c0 + tx * 8;
        *(float4*)&C[base] = v0;
        *(float4*)&C[base + 4] = v1;
    }
}

// ---------------------------------------------------------------------------
// Parallel STABLE counting-sort CSR (R19-proven).
// ---------------------------------------------------------------------------
__global__ __launch_bounds__(256)
void csr_build(const int* __restrict__ ei, const int* __restrict__ cur, int npg,
               int* __restrict__ degS, float* __restrict__ dinvS,
               int* __restrict__ startsS, int* __restrict__ slotsS) {
    __shared__ int cul[EPG];
    __shared__ short dstv[EPG];
    __shared__ unsigned char rnk[EPG];
    __shared__ int h[32][256];
    __shared__ int cnt[256];
    __shared__ int st[256];
    const int g = blockIdx.x;
    const int t = threadIdx.x;
    const int lane = t & 63;
    const int wv = t >> 6;

    for (int i = t; i < 32 * 256; i += 256) ((int*)h)[i] = 0;
    for (int e = t; e < EPG; e += 256) {
        size_t idx = (size_t)g * EPG + e;
        int cu = cur[g * 256 + (ei[idx] - g * 256)];
        int cv = cur[g * 256 + (ei[E_TOT + idx] - g * 256)];
        bool valid = (cu >= 0 && cv >= 0);
        cul[e] = cu;
        dstv[e] = valid ? (short)cv : (short)256;
    }
    __syncthreads();
    for (int c = wv; c < 32; c += 4) {
        int e = c * 64 + lane;
        int d = (int)dstv[e];
        unsigned long long m = ~0ULL;
#pragma unroll
        for (int b = 0; b < 9; ++b) {
            unsigned long long bb = __ballot((d >> b) & 1);
            m &= ((d >> b) & 1) ? bb : ~bb;
        }
        int r = __popcll(m & ((1ULL << lane) - 1ULL));
        rnk[e] = (unsigned char)r;
        if (r == 0 && d < 256) h[c][d] = __popcll(m);
    }
    __syncthreads();
    if (t < npg) {
        int run = 0;
        for (int c = 0; c < 32; ++c) { int v = h[c][t]; h[c][t] = run; run += v; }
        cnt[t] = run;
        degS[g * npg + t] = run + 1;
        dinvS[g * npg + t] = 1.0f / sqrtf((float)(run + 1));
    }
    __syncthreads();
    if (t == 0) {
        int run = 0;
        for (int i = 0; i < npg; ++i) { st[i] = run; run += cnt[i]; }
    }
    __syncthreads();
    if (t < npg) startsS[g * npg + t] = g * EPG + st[t];
    for (int e = t; e < EPG; e += 256) {
        int d = (int)dstv[e];
        if (d < npg) {
            int slot = st[d] + h[e >> 6][d] + (int)rnk[e];
            slotsS[g * EPG + slot] = g * npg + cul[e];
        }
    }
}

// ---------------------------------------------------------------------------
// conv + relu + pool score with XCD-locality swizzle (R18-proven).
// ---------------------------------------------------------------------------
__global__ __launch_bounds__(256)
void agg_score(const int* __restrict__ degS, const float* __restrict__ dinvS,
               const int* __restrict__ startsS, const int* __restrict__ slotsS,
               const float* __restrict__ HL, float* __restrict__ H2,
               const float* __restrict__ bias, const float* __restrict__ pw,
               float* __restrict__ score, int nOver8) {
    __shared__ float vrow[256];
    const int node = (blockIdx.x & 7) * nOver8 + (blockIdx.x >> 3);
    const int t = threadIdx.x;
    const int cntE = degS[node] - 1;
    const float degF = (float)degS[node];
    const float dn = dinvS[node];
    const int s0 = startsS[node];
    float acc = 0.f;
    for (int j = 0; j < cntE; ++j) {
        int srcg = slotsS[s0 + j];
        acc += dinvS[srcg] * HL[(size_t)srcg * 256 + t];
    }
    float v = acc * dn + HL[(size_t)node * 256 + t] / degF + bias[t];
    v = fmaxf(v, 0.f);
    H2[(size_t)node * 256 + t] = v;
    vrow[t] = v;
    __syncthreads();
    if (t < 64) {
        const int lane = t;
        float pr = 0.f, s2p = 0.f;
        for (int j = 0; j < 4; ++j) {
            int f = lane + 64 * j;
            float w = pw[f];
            pr += vrow[f] * w;
            s2p += w * w;
        }
        for (int off = 32; off; off >>= 1) {
            pr += __shfl_down(pr, off, 64);
            s2p += __shfl_down(s2p, off, 64);
        }
        s2p = __shfl(s2p, 0, 64);
        if (lane == 0) score[node] = tanhf(pr / sqrtf(s2p));
    }
}

// ---------------------------------------------------------------------------
__global__ __launch_bounds__(256)
void topk_cur(const float* __restrict__ score, int npg, int k,
              int* __restrict__ kept, int* __restrict__ cur) {
    __shared__ float ss[256];
    __shared__ int si_[256];
    __shared__ int rankOf[256];
    const int g = blockIdx.x;
    const int t = threadIdx.x;
    if (t < npg) { ss[t] = score[g * npg + t]; si_[t] = t; }
    else         { ss[t] = -INFINITY; si_[t] = 0x7FFFFFFF; }
    for (int size = 2; size <= 256; size <<= 1) {
        for (int stride = size >> 1; stride > 0; stride >>= 1) {
            __syncthreads();
            int i = t, j = t ^ stride;
            if (j > i) {
                float a = ss[i], b = ss[j];
                int ia = si_[i], ib = si_[j];
                bool inOrder = (a > b) || (a == b && ia < ib);
                bool desc = ((i & size) == 0);
                if (desc ? !inOrder : inOrder) {
                    ss[i] = b; ss[j] = a; si_[i] = ib; si_[j] = ia;
                }
            }
        }
    }
    __syncthreads();
    rankOf[t] = -1;
    __syncthreads();
    if (t < k) {
        kept[g * k + t] = g * npg + si_[t];
        rankOf[si_[t]] = t;
    }
    __syncthreads();
    {
        int v = g * 256 + t;
        int c = cur[v];
        cur[v] = (c >= 0) ? rankOf[c] : -1;
    }
}

__global__ __launch_bounds__(256)
void pool_gather(const int* __restrict__ kept, const float* __restrict__ score,
                 const float* __restrict__ H2, float* __restrict__ OUT) {
    const int j = blockIdx.x;
    const int t = threadIdx.x;
    const int o = kept[j];
    OUT[(size_t)j * 256 + t] = H2[(size_t)o * 256 + t] * score[o];
}

__global__ __launch_bounds__(256)
void readout(const float* __restrict__ X, int k, float* __restrict__ outacc,
             int first) {
    const int g = blockIdx.x;
    const int t = threadIdx.x;
    const float* base = X + (size_t)g * k * 256 + t;
    float mx = -INFINITY, sm = 0.f;
    for (int n = 0; n < k; ++n) {
        float vv = base[(size_t)n * 256];
        mx = fmaxf(mx, vv);
        sm += vv;
    }
    float mean = sm / (float)k;
    if (first) {
        outacc[g * 512 + t] = mx;
        outacc[g * 512 + 256 + t] = mean;
    } else {
        outacc[g * 512 + t] += mx;
        outacc[g * 512 + 256 + t] += mean;
    }
}

__global__ __launch_bounds__(256)
void mlp_head(const float* __restrict__ outacc,
              const float* __restrict__ l1w, const float* __restrict__ l1b,
              const float* __restrict__ l2w, const float* __restrict__ l2b,
              const float* __restrict__ l3w, const float* __restrict__ l3b,
              float* __restrict__ out) {
    __shared__ float row[512];
    __shared__ float h1[256];
    __shared__ float h2[128];
    const int g = blockIdx.x;
    const int t = threadIdx.x;
    row[t] = outacc[g * 512 + t];
    row[256 + t] = outacc[g * 512 + 256 + t];
    __syncthreads();
    {
        float a = l1b[t];
        for (int j = 0; j < 512; ++j) a += row[j] * l1w[j * 256 + t];
        h1[t] = fmaxf(a, 0.f);
    }
    __syncthreads();
    if (t < 128) {
        float a2 = l2b[t];
        for (int j = 0; j < 256; ++j) a2 += h1[j] * l2w[j * 128 + t];
        h2[t] = fmaxf(a2, 0.f);
    }
    __syncthreads();
    if (t == 0) {
        float l0 = l3b[0], l1 = l3b[1];
        for (int j = 0; j < 128; ++j) {
            float h = h2[j];
            l0 += h * l3w[j * 2 + 0];
            l1 += h * l3w[j * 2 + 1];
        }
        float m = fmaxf(l0, l1);
        float lse = m + logf(expf(l0 - m) + expf(l1 - m));
        out[g * 2 + 0] = l0 - lse;
        out[g * 2 + 1] = l1 - lse;
    }
}

// ============================================================================
// Fallback: proven R15 monolith (used only if ws_size is too small)
// ============================================================================
__global__ __launch_bounds__(256, 1)
void gnn_mono(const float* __restrict__ x, const int* __restrict__ ei,
              const float* __restrict__ gw0, const float* __restrict__ gb0,
              const float* __restrict__ gw1, const float* __restrict__ gb1,
              const float* __restrict__ gw2, const float* __restrict__ gb2,
              const float* __restrict__ pw0, const float* __restrict__ pw1,
              const float* __restrict__ pw2,
              const float* __restrict__ l1w, const float* __restrict__ l1b,
              const float* __restrict__ l2w, const float* __restrict__ l2b,
              const float* __restrict__ l3w, const float* __restrict__ l3b,
              float* __restrict__ out, float* __restrict__ ws) {
    const int g = blockIdx.x;
    const int t = threadIdx.x;
    float* P = ws + (size_t)g * HF * 256;
    float* Q = ws + (size_t)G_GRAPHS * HF * 256 + (size_t)g * HF * 256;
    __shared__ int   eb[EPG];
    __shared__ int   slots[EPG];
    __shared__ int   curID[256];
    __shared__ int   cntL[256];
    __shared__ int   startL[256];
    __shared__ float degF[256];
    __shared__ float dinv[256];
    __shared__ float sa[256];
    __shared__ float ss[256];
    __shared__ int   si_[256];
    __shared__ float scoreV[256];
    __shared__ int   kept[128];
    __shared__ int   rankOf[256];
    __shared__ float row[512];
    for (int e = t; e < EPG; e += 256) {
        size_t idx = (size_t)g * EPG + e;
        eb[e] = ((ei[idx] - g * 256) << 8) | (ei[E_TOT + idx] - g * 256);
    }
    curID[t] = t;
    float accMx = 0.f, accMn = 0.f;
    const float* GW[3] = {gw0, gw1, gw2};
    const float* GB[3] = {gb0, gb1, gb2};
    const float* PW[3] = {pw0, pw1, pw2};
    const int kk[3] = {128, 64, 32};
    int npg = 256;
    __syncthreads();
    for (int s = 0; s < 3; ++s) {
        const int knext = kk[s];
        {
            const float* Wp = GW[s];
            const int K = (s == 0) ? FIN : HF;
            for (int n = 0; n < npg; ++n) {
                if (s == 0) { if (t < FIN) sa[t] = x[(size_t)(g * 256 + n) * FIN + t]; }
                else sa[t] = P[(size_t)n * HF + t];
                __syncthreads();
                float a = 0.f;
                for (int k2 = 0; k2 < K; ++k2) a += sa[k2] * Wp[k2 * HF + t];
                Q[(size_t)n * HF + t] = a;
                __syncthreads();
            }
        }
        cntL[t] = 0;
        __syncthreads();
        for (int e = t; e < EPG; e += 256) {
            int p = eb[e];
            int cu = curID[p >> 8], cv = curID[p & 255];
            if (cu >= 0 && cv >= 0) atomicAdd(&cntL[cv], 1);
        }
        __syncthreads();
        if (t == 0) { int run = 0; for (int i = 0; i < npg; ++i) { startL[i] = run; run += cntL[i]; } }
        __syncthreads();
        if (t < npg) {
            float d = (float)cntL[t] + 1.0f;
            degF[t] = d;
            dinv[t] = 1.0f / sqrtf(d);
            int c = startL[t];
            for (int e = 0; e < EPG; ++e) {
                int p = eb[e];
                int cu = curID[p >> 8], cv = curID[p & 255];
                if (cu >= 0 && cv >= 0 && cv == t) slots[c++] = e;
            }
        }
        __syncthreads();
        {
            const float bb = GB[s][t];
            for (int n = 0; n < npg; ++n) {
                float acc = 0.f;
                const int s0 = startL[n], s1 = s0 + cntL[n];
                for (int j = s0; j < s1; ++j) {
                    int scur = curID[eb[slots[j]] >> 8];
                    acc += dinv[scur] * Q[(size_t)scur * HF + t];
                }
                float v = acc * dinv[n] + Q[(size_t)n * HF + t] / degF[n] + bb;
                P[(size_t)n * HF + t] = fmaxf(v, 0.f);
            }
        }
        __syncthreads();
        {
            const float* pwp = PW[s];
            const int lane = t & 63, wv = t >> 6;
            float s2p = 0.f;
            for (int j = 0; j < 4; ++j) { float w = pwp[lane + 64 * j]; s2p += w * w; }
            for (int off = 32; off; off >>= 1) s2p += __shfl_down(s2p, off, 64);
            s2p = __shfl(s2p, 0, 64);
            const float nw = sqrtf(s2p);
            for (int n = wv; n < npg; n += 4) {
                float pr = 0.f;
                for (int j = 0; j < 4; ++j) { int f = lane + 64 * j; pr += P[(size_t)n * HF + f] * pwp[f]; }
                for (int off = 32; off; off >>= 1) pr += __shfl_down(pr, off, 64);
                if (lane == 0) scoreV[n] = tanhf(pr / nw);
            }
        }
        __syncthreads();
        if (t < npg) { ss[t] = scoreV[t]; si_[t] = t; }
        else         { ss[t] = -INFINITY; si_[t] = 0x7FFFFFFF; }
        for (int size = 2; size <= 256; size <<= 1) {
            for (int stride = size >> 1; stride > 0; stride >>= 1) {
                __syncthreads();
                int i = t, j = t ^ stride;
                if (j > i) {
                    float a = ss[i], b = ss[j];
                    int ia = si_[i], ib = si_[j];
                    bool inOrder = (a > b) || (a == b && ia < ib);
                    bool desc = ((i & size) == 0);
                    if (desc ? !inOrder : inOrder) { ss[i] = b; ss[j] = a; si_[i] = ib; si_[j] = ia; }
                }
            }
        }
        __syncthreads();
        if (t < knext) kept[t] = si_[t];
        __syncthreads();
        {
            float mx = -INFINITY, sm = 0.f;
            for (int n = 0; n < knext; ++n) {
                int o = kept[n];
                float vv = P[(size_t)o * HF + t] * scoreV[o];
                Q[(size_t)n * HF + t] = vv;
                mx = fmaxf(mx, vv);
                sm += vv;
            }
            accMx += mx;
            accMn += sm / (float)knext;
        }
        rankOf[t] = -1;
        __syncthreads();
        if (t < knext) rankOf[kept[t]] = t;
        __syncthreads();
        { int c = curID[t]; curID[t] = (c >= 0) ? rankOf[c] : -1; }
        __syncthreads();
        { float* tmp = P; P = Q; Q = tmp; }
        npg = knext;
    }
    row[t] = accMx;
    row[256 + t] = accMn;
    __syncthreads();
    { float a = l1b[t]; for (int j = 0; j < 512; ++j) a += row[j] * l1w[j * 256 + t]; scoreV[t] = fmaxf(a, 0.f); }
    __syncthreads();
    if (t < 128) { float a2 = l2b[t]; for (int j = 0; j < 256; ++j) a2 += scoreV[j] * l2w[j * 128 + t]; sa[t] = fmaxf(a2, 0.f); }
    __syncthreads();
    if (t == 0) {
        float l0 = l3b[0], l1 = l3b[1];
        for (int j = 0; j < 128; ++j) { float h = sa[j]; l0 += h * l3w[j * 2 + 0]; l1 += h * l3w[j * 2 + 1]; }
        float m = fmaxf(l0, l1);
        float lse = m + logf(expf(l0 - m) + expf(l1 - m));
        out[g * 2 + 0] = l0 - lse;
        out[g * 2 + 1] = l1 - lse;
    }
}

// ============================================================================
extern "C" void kernel_launch(void* const* d_in, const int* in_sizes, int n_in,
                              void* d_out, int out_size, void* d_ws, size_t ws_size,
                              hipStream_t stream) {
    const float* x   = (const float*)d_in[0];
    const int*   ei  = (const int*)d_in[1];
    const float* gw0 = (const float*)d_in[3];
    const float* gb0 = (const float*)d_in[4];
    const float* gw1 = (const float*)d_in[5];
    const float* gb1 = (const float*)d_in[6];
    const float* gw2 = (const float*)d_in[7];
    const float* gb2 = (const float*)d_in[8];
    const float* pw0 = (const float*)d_in[9];
    const float* pw1 = (const float*)d_in[10];
    const float* pw2 = (const float*)d_in[11];
    const float* l1w = (const float*)d_in[12];
    const float* l1b = (const float*)d_in[13];
    const float* l2w = (const float*)d_in[14];
    const float* l2b = (const float*)d_in[15];
    const float* l3w = (const float*)d_in[16];
    const float* l3b = (const float*)d_in[17];
    float* out = (float*)d_out;

    const size_t SLAB = (size_t)65536 * 256;
    char* p = (char*)d_ws;
    float* P      = (float*)p; p += SLAB * 4;
    float* Q      = (float*)p; p += SLAB * 4;
    int*   cur    = (int*)p;   p += (size_t)65536 * 4;
    int*   degS   = (int*)p;   p += (size_t)65536 * 4;
    float* dinvS  = (float*)p; p += (size_t)65536 * 4;
    int*   starts = (int*)p;   p += (size_t)65536 * 4;
    int*   slotsS = (int*)p;   p += (size_t)E_TOT * 4;
    float* score  = (float*)p; p += (size_t)65536 * 4;
    int*   kept   = (int*)p;   p += (size_t)32768 * 4;
    float* outacc = (float*)p; p += (size_t)G_GRAPHS * 512 * 4;
    const size_t needed = (size_t)(p - (char*)d_ws);

    if (ws_size < needed) {
        gnn_mono<<<G_GRAPHS, 256, 0, stream>>>(
            x, ei, gw0, gb0, gw1, gb1, gw2, gb2, pw0, pw1, pw2,
            l1w, l1b, l2w, l2b, l3w, l3b, out, (float*)d_ws);
        return;
    }

    init_cur<<<(G_GRAPHS * 256 + 255) / 256, 256, 0, stream>>>(cur);

    const int   npg[3] = {256, 128, 64};
    const int   kk[3]  = {128, 64, 32};
    const int   Ns[3]  = {65536, 32768, 16384};
    const float* GW[3] = {gw0, gw1, gw2};
    const float* GB[3] = {gb0, gb1, gb2};
    const float* PW[3] = {pw0, pw1, pw2};

    float* HLs[3]   = {P, Q, P};
    float* H2s[3]   = {Q, P, Q};
    float* POOLs[3] = {P, Q, P};

    for (int s = 0; s < 3; ++s) {
        const int n = Ns[s];
        const int k = kk[s];
        // 1) GEMM (64x128 tile, conflict-free staging)
        if (s == 0) {
            dim3 grid(n / 64, 2);
            gemm_v2<FIN><<<grid, 256, 0, stream>>>(x, GW[s], HLs[s]);
        } else {
            dim3 grid(n / 64, 2);
            gemm_v2<HF><<<grid, 256, 0, stream>>>(POOLs[s - 1], GW[s], HLs[s]);
        }
        // 2) CSR (parallel stable counting sort)
        csr_build<<<G_GRAPHS, 256, 0, stream>>>(ei, cur, npg[s],
                                                degS, dinvS, starts, slotsS);
        // 3) conv + score (XCD-swizzled node mapping)
        agg_score<<<n, 256, 0, stream>>>(degS, dinvS, starts, slotsS,
                                         HLs[s], H2s[s], GB[s], PW[s], score,
                                         n / 8);
        // 4) top-k + cur update
        topk_cur<<<G_GRAPHS, 256, 0, stream>>>(score, npg[s], k, kept, cur);
        // 5) pool
        pool_gather<<<G_GRAPHS * k, 256, 0, stream>>>(kept, score, H2s[s], POOLs[s]);
        // 6) readout
        readout<<<G_GRAPHS, 256, 0, stream>>>(POOLs[s], k, outacc, s == 0 ? 1 : 0);
    }

    mlp_head<<<G_GRAPHS, 256, 0, stream>>>(outacc, l1w, l1b, l2w, l2b, l3w, l3b, out);
}

// Round 21
// 558.677 us; speedup vs baseline: 2.1076x; 1.0810x over previous
//
#include <hip/hip_runtime.h>
#include <hip/hip_bf16.h>
#include <math.h>

#define G_GRAPHS 256
#define EPG 2048
#define E_TOT 524288
#define HF 256
#define FIN 128

// ============================================================================
__global__ void init_cur(int* __restrict__ cur) {
    int i = blockIdx.x * blockDim.x + threadIdx.x;
    if (i < G_GRAPHS * 256) cur[i] = i & 255;
}

// ---------------------------------------------------------------------------
// C[N x 256] = A[N x K] @ W[K x 256], fp32, k-ascending accumulation.
// (R20-proven: conflict-free staging, 64x128 tile, 4x8/thread)
// ---------------------------------------------------------------------------
template <int K>
__global__ __launch_bounds__(256)
void gemm_v2(const float* __restrict__ A, const float* __restrict__ W,
             float* __restrict__ C) {
    __shared__ float As2[64 * 65];
    __shared__ float Ws[64 * 136];
    const int tid = threadIdx.x;
    const int tx = tid & 15;
    const int ty = tid >> 4;
    const int r0 = blockIdx.x * 64;
    const int c0 = blockIdx.y * 128;
    float acc[4][8] = {{0.f}};
    for (int k0 = 0; k0 < K; k0 += 64) {
        {
            int r = tid >> 4;
            int c = tid & 15;
#pragma unroll
            for (int it = 0; it < 4; ++it) {
                float4 v = *(const float4*)&A[(size_t)(r0 + r) * K + k0 + 4 * c];
                float* dst = &As2[r * 65 + 4 * c];
                dst[0] = v.x; dst[1] = v.y; dst[2] = v.z; dst[3] = v.w;
                r += 16;
            }
        }
        {
            int kk = tid >> 5;
            int c = tid & 31;
#pragma unroll
            for (int it = 0; it < 8; ++it) {
                float4 v = *(const float4*)&W[(size_t)(k0 + kk) * 256 + c0 + 4 * c];
                *(float4*)&Ws[kk * 136 + 4 * c] = v;
                kk += 8;
            }
        }
        __syncthreads();
#pragma unroll 4
        for (int kk = 0; kk < 64; ++kk) {
            float av0 = As2[(ty * 4 + 0) * 65 + kk];
            float av1 = As2[(ty * 4 + 1) * 65 + kk];
            float av2 = As2[(ty * 4 + 2) * 65 + kk];
            float av3 = As2[(ty * 4 + 3) * 65 + kk];
            float4 w0 = *(const float4*)&Ws[kk * 136 + tx * 8];
            float4 w1 = *(const float4*)&Ws[kk * 136 + tx * 8 + 4];
            float wv[8] = {w0.x, w0.y, w0.z, w0.w, w1.x, w1.y, w1.z, w1.w};
#pragma unroll
            for (int cc = 0; cc < 8; ++cc) {
                acc[0][cc] += av0 * wv[cc];
                acc[1][cc] += av1 * wv[cc];
                acc[2][cc] += av2 * wv[cc];
                acc[3][cc] += av3 * wv[cc];
            }
        }
        __syncthreads();
    }
#pragma unroll
    for (int i = 0; i < 4; ++i) {
        float4 v0 = make_float4(acc[i][0], acc[i][1], acc[i][2], acc[i][3]);
        float4 v1 = make_float4(acc[i][4], acc[i][5], acc[i][6], acc[i][7]);
        size_t base = (size_t)(r0 + ty * 4 + i) * 256 + c0 + tx * 8;
        *(float4*)&C[base] = v0;
        *(float4*)&C[base + 4] = v1;
    }
}

// ---------------------------------------------------------------------------
// Parallel STABLE counting-sort CSR. Phase C now also packs dinv(src) next to
// the src id (same 1/sqrtf(cnt+1) expression as dinvS => bit-identical value).
// ---------------------------------------------------------------------------
__global__ __launch_bounds__(256)
void csr_build(const int* __restrict__ ei, const int* __restrict__ cur, int npg,
               int* __restrict__ degS, float* __restrict__ dinvS,
               int* __restrict__ startsS, int2* __restrict__ slots2) {
    __shared__ int cul[EPG];
    __shared__ short dstv[EPG];
    __shared__ unsigned char rnk[EPG];
    __shared__ int h[32][256];
    __shared__ int cnt[256];
    __shared__ int st[256];
    const int g = blockIdx.x;
    const int t = threadIdx.x;
    const int lane = t & 63;
    const int wv = t >> 6;

    for (int i = t; i < 32 * 256; i += 256) ((int*)h)[i] = 0;
    for (int e = t; e < EPG; e += 256) {
        size_t idx = (size_t)g * EPG + e;
        int cu = cur[g * 256 + (ei[idx] - g * 256)];
        int cv = cur[g * 256 + (ei[E_TOT + idx] - g * 256)];
        bool valid = (cu >= 0 && cv >= 0);
        cul[e] = cu;
        dstv[e] = valid ? (short)cv : (short)256;
    }
    __syncthreads();
    for (int c = wv; c < 32; c += 4) {
        int e = c * 64 + lane;
        int d = (int)dstv[e];
        unsigned long long m = ~0ULL;
#pragma unroll
        for (int b = 0; b < 9; ++b) {
            unsigned long long bb = __ballot((d >> b) & 1);
            m &= ((d >> b) & 1) ? bb : ~bb;
        }
        int r = __popcll(m & ((1ULL << lane) - 1ULL));
        rnk[e] = (unsigned char)r;
        if (r == 0 && d < 256) h[c][d] = __popcll(m);
    }
    __syncthreads();
    if (t < npg) {
        int run = 0;
        for (int c = 0; c < 32; ++c) { int v = h[c][t]; h[c][t] = run; run += v; }
        cnt[t] = run;
        degS[g * npg + t] = run + 1;
        dinvS[g * npg + t] = 1.0f / sqrtf((float)(run + 1));
    }
    __syncthreads();
    if (t == 0) {
        int run = 0;
        for (int i = 0; i < npg; ++i) { st[i] = run; run += cnt[i]; }
    }
    __syncthreads();
    if (t < npg) startsS[g * npg + t] = g * EPG + st[t];
    for (int e = t; e < EPG; e += 256) {
        int d = (int)dstv[e];
        if (d < npg) {
            int slot = st[d] + h[e >> 6][d] + (int)rnk[e];
            int cu = cul[e];
            float dv = 1.0f / sqrtf((float)(cnt[cu] + 1));   // == dinvS[src]
            slots2[g * EPG + slot] = make_int2(g * npg + cu, __float_as_int(dv));
        }
    }
}

// ---------------------------------------------------------------------------
// conv + relu + pool score with XCD swizzle; edge loop batched (8/4/1) for
// memory-level parallelism; accumulation order unchanged (ascending j).
// ---------------------------------------------------------------------------
__global__ __launch_bounds__(256)
void agg_score(const int* __restrict__ degS, const float* __restrict__ dinvS,
               const int* __restrict__ startsS, const int2* __restrict__ slots2,
               const float* __restrict__ HL, float* __restrict__ H2,
               const float* __restrict__ bias, const float* __restrict__ pw,
               float* __restrict__ score, int nOver8) {
    __shared__ float vrow[256];
    const int node = (blockIdx.x & 7) * nOver8 + (blockIdx.x >> 3);
    const int t = threadIdx.x;
    const int cntE = degS[node] - 1;
    const float degF = (float)degS[node];
    const float dn = dinvS[node];
    const int2* sl = slots2 + startsS[node];
    float acc = 0.f;
    int j = 0;
    for (; j + 8 <= cntE; j += 8) {
        int2 s[8];
#pragma unroll
        for (int u = 0; u < 8; ++u) s[u] = sl[j + u];
        float hv[8];
#pragma unroll
        for (int u = 0; u < 8; ++u) hv[u] = HL[(size_t)s[u].x * 256 + t];
#pragma unroll
        for (int u = 0; u < 8; ++u) acc += __int_as_float(s[u].y) * hv[u];
    }
    for (; j + 4 <= cntE; j += 4) {
        int2 s[4];
#pragma unroll
        for (int u = 0; u < 4; ++u) s[u] = sl[j + u];
        float hv[4];
#pragma unroll
        for (int u = 0; u < 4; ++u) hv[u] = HL[(size_t)s[u].x * 256 + t];
#pragma unroll
        for (int u = 0; u < 4; ++u) acc += __int_as_float(s[u].y) * hv[u];
    }
    for (; j < cntE; ++j) {
        int2 sv = sl[j];
        acc += __int_as_float(sv.y) * HL[(size_t)sv.x * 256 + t];
    }
    float v = acc * dn + HL[(size_t)node * 256 + t] / degF + bias[t];
    v = fmaxf(v, 0.f);
    H2[(size_t)node * 256 + t] = v;
    vrow[t] = v;
    __syncthreads();
    if (t < 64) {
        const int lane = t;
        float pr = 0.f, s2p = 0.f;
        for (int jj = 0; jj < 4; ++jj) {
            int f = lane + 64 * jj;
            float w = pw[f];
            pr += vrow[f] * w;
            s2p += w * w;
        }
        for (int off = 32; off; off >>= 1) {
            pr += __shfl_down(pr, off, 64);
            s2p += __shfl_down(s2p, off, 64);
        }
        s2p = __shfl(s2p, 0, 64);
        if (lane == 0) score[node] = tanhf(pr / sqrtf(s2p));
    }
}

// ---------------------------------------------------------------------------
__global__ __launch_bounds__(256)
void topk_cur(const float* __restrict__ score, int npg, int k,
              int* __restrict__ kept, int* __restrict__ cur) {
    __shared__ float ss[256];
    __shared__ int si_[256];
    __shared__ int rankOf[256];
    const int g = blockIdx.x;
    const int t = threadIdx.x;
    if (t < npg) { ss[t] = score[g * npg + t]; si_[t] = t; }
    else         { ss[t] = -INFINITY; si_[t] = 0x7FFFFFFF; }
    for (int size = 2; size <= 256; size <<= 1) {
        for (int stride = size >> 1; stride > 0; stride >>= 1) {
            __syncthreads();
            int i = t, j = t ^ stride;
            if (j > i) {
                float a = ss[i], b = ss[j];
                int ia = si_[i], ib = si_[j];
                bool inOrder = (a > b) || (a == b && ia < ib);
                bool desc = ((i & size) == 0);
                if (desc ? !inOrder : inOrder) {
                    ss[i] = b; ss[j] = a; si_[i] = ib; si_[j] = ia;
                }
            }
        }
    }
    __syncthreads();
    rankOf[t] = -1;
    __syncthreads();
    if (t < k) {
        kept[g * k + t] = g * npg + si_[t];
        rankOf[si_[t]] = t;
    }
    __syncthreads();
    {
        int v = g * 256 + t;
        int c = cur[v];
        cur[v] = (c >= 0) ? rankOf[c] : -1;
    }
}

__global__ __launch_bounds__(256)
void pool_gather(const int* __restrict__ kept, const float* __restrict__ score,
                 const float* __restrict__ H2, float* __restrict__ OUT) {
    const int j = blockIdx.x;
    const int t = threadIdx.x;
    const int o = kept[j];
    OUT[(size_t)j * 256 + t] = H2[(size_t)o * 256 + t] * score[o];
}

__global__ __launch_bounds__(256)
void readout(const float* __restrict__ X, int k, float* __restrict__ outacc,
             int first) {
    const int g = blockIdx.x;
    const int t = threadIdx.x;
    const float* base = X + (size_t)g * k * 256 + t;
    float mx = -INFINITY, sm = 0.f;
    for (int n = 0; n < k; ++n) {
        float vv = base[(size_t)n * 256];
        mx = fmaxf(mx, vv);
        sm += vv;
    }
    float mean = sm / (float)k;
    if (first) {
        outacc[g * 512 + t] = mx;
        outacc[g * 512 + 256 + t] = mean;
    } else {
        outacc[g * 512 + t] += mx;
        outacc[g * 512 + 256 + t] += mean;
    }
}

__global__ __launch_bounds__(256)
void mlp_head(const float* __restrict__ outacc,
              const float* __restrict__ l1w, const float* __restrict__ l1b,
              const float* __restrict__ l2w, const float* __restrict__ l2b,
              const float* __restrict__ l3w, const float* __restrict__ l3b,
              float* __restrict__ out) {
    __shared__ float row[512];
    __shared__ float h1[256];
    __shared__ float h2[128];
    const int g = blockIdx.x;
    const int t = threadIdx.x;
    row[t] = outacc[g * 512 + t];
    row[256 + t] = outacc[g * 512 + 256 + t];
    __syncthreads();
    {
        float a = l1b[t];
        for (int j = 0; j < 512; ++j) a += row[j] * l1w[j * 256 + t];
        h1[t] = fmaxf(a, 0.f);
    }
    __syncthreads();
    if (t < 128) {
        float a2 = l2b[t];
        for (int j = 0; j < 256; ++j) a2 += h1[j] * l2w[j * 128 + t];
        h2[t] = fmaxf(a2, 0.f);
    }
    __syncthreads();
    if (t == 0) {
        float l0 = l3b[0], l1 = l3b[1];
        for (int j = 0; j < 128; ++j) {
            float h = h2[j];
            l0 += h * l3w[j * 2 + 0];
            l1 += h * l3w[j * 2 + 1];
        }
        float m = fmaxf(l0, l1);
        float lse = m + logf(expf(l0 - m) + expf(l1 - m));
        out[g * 2 + 0] = l0 - lse;
        out[g * 2 + 1] = l1 - lse;
    }
}

// ============================================================================
// Fallback: proven R15 monolith (used only if ws_size is too small)
// ============================================================================
__global__ __launch_bounds__(256, 1)
void gnn_mono(const float* __restrict__ x, const int* __restrict__ ei,
              const float* __restrict__ gw0, const float* __restrict__ gb0,
              const float* __restrict__ gw1, const float* __restrict__ gb1,
              const float* __restrict__ gw2, const float* __restrict__ gb2,
              const float* __restrict__ pw0, const float* __restrict__ pw1,
              const float* __restrict__ pw2,
              const float* __restrict__ l1w, const float* __restrict__ l1b,
              const float* __restrict__ l2w, const float* __restrict__ l2b,
              const float* __restrict__ l3w, const float* __restrict__ l3b,
              float* __restrict__ out, float* __restrict__ ws) {
    const int g = blockIdx.x;
    const int t = threadIdx.x;
    float* P = ws + (size_t)g * HF * 256;
    float* Q = ws + (size_t)G_GRAPHS * HF * 256 + (size_t)g * HF * 256;
    __shared__ int   eb[EPG];
    __shared__ int   slots[EPG];
    __shared__ int   curID[256];
    __shared__ int   cntL[256];
    __shared__ int   startL[256];
    __shared__ float degF[256];
    __shared__ float dinv[256];
    __shared__ float sa[256];
    __shared__ float ss[256];
    __shared__ int   si_[256];
    __shared__ float scoreV[256];
    __shared__ int   kept[128];
    __shared__ int   rankOf[256];
    __shared__ float row[512];
    for (int e = t; e < EPG; e += 256) {
        size_t idx = (size_t)g * EPG + e;
        eb[e] = ((ei[idx] - g * 256) << 8) | (ei[E_TOT + idx] - g * 256);
    }
    curID[t] = t;
    float accMx = 0.f, accMn = 0.f;
    const float* GW[3] = {gw0, gw1, gw2};
    const float* GB[3] = {gb0, gb1, gb2};
    const float* PW[3] = {pw0, pw1, pw2};
    const int kk[3] = {128, 64, 32};
    int npg = 256;
    __syncthreads();
    for (int s = 0; s < 3; ++s) {
        const int knext = kk[s];
        {
            const float* Wp = GW[s];
            const int K = (s == 0) ? FIN : HF;
            for (int n = 0; n < npg; ++n) {
                if (s == 0) { if (t < FIN) sa[t] = x[(size_t)(g * 256 + n) * FIN + t]; }
                else sa[t] = P[(size_t)n * HF + t];
                __syncthreads();
                float a = 0.f;
                for (int k2 = 0; k2 < K; ++k2) a += sa[k2] * Wp[k2 * HF + t];
                Q[(size_t)n * HF + t] = a;
                __syncthreads();
            }
        }
        cntL[t] = 0;
        __syncthreads();
        for (int e = t; e < EPG; e += 256) {
            int p = eb[e];
            int cu = curID[p >> 8], cv = curID[p & 255];
            if (cu >= 0 && cv >= 0) atomicAdd(&cntL[cv], 1);
        }
        __syncthreads();
        if (t == 0) { int run = 0; for (int i = 0; i < npg; ++i) { startL[i] = run; run += cntL[i]; } }
        __syncthreads();
        if (t < npg) {
            float d = (float)cntL[t] + 1.0f;
            degF[t] = d;
            dinv[t] = 1.0f / sqrtf(d);
            int c = startL[t];
            for (int e = 0; e < EPG; ++e) {
                int p = eb[e];
                int cu = curID[p >> 8], cv = curID[p & 255];
                if (cu >= 0 && cv >= 0 && cv == t) slots[c++] = e;
            }
        }
        __syncthreads();
        {
            const float bb = GB[s][t];
            for (int n = 0; n < npg; ++n) {
                float acc = 0.f;
                const int s0 = startL[n], s1 = s0 + cntL[n];
                for (int j = s0; j < s1; ++j) {
                    int scur = curID[eb[slots[j]] >> 8];
                    acc += dinv[scur] * Q[(size_t)scur * HF + t];
                }
                float v = acc * dinv[n] + Q[(size_t)n * HF + t] / degF[n] + bb;
                P[(size_t)n * HF + t] = fmaxf(v, 0.f);
            }
        }
        __syncthreads();
        {
            const float* pwp = PW[s];
            const int lane = t & 63, wv = t >> 6;
            float s2p = 0.f;
            for (int j = 0; j < 4; ++j) { float w = pwp[lane + 64 * j]; s2p += w * w; }
            for (int off = 32; off; off >>= 1) s2p += __shfl_down(s2p, off, 64);
            s2p = __shfl(s2p, 0, 64);
            const float nw = sqrtf(s2p);
            for (int n = wv; n < npg; n += 4) {
                float pr = 0.f;
                for (int j = 0; j < 4; ++j) { int f = lane + 64 * j; pr += P[(size_t)n * HF + f] * pwp[f]; }
                for (int off = 32; off; off >>= 1) pr += __shfl_down(pr, off, 64);
                if (lane == 0) scoreV[n] = tanhf(pr / nw);
            }
        }
        __syncthreads();
        if (t < npg) { ss[t] = scoreV[t]; si_[t] = t; }
        else         { ss[t] = -INFINITY; si_[t] = 0x7FFFFFFF; }
        for (int size = 2; size <= 256; size <<= 1) {
            for (int stride = size >> 1; stride > 0; stride >>= 1) {
                __syncthreads();
                int i = t, j = t ^ stride;
                if (j > i) {
                    float a = ss[i], b = ss[j];
                    int ia = si_[i], ib = si_[j];
                    bool inOrder = (a > b) || (a == b && ia < ib);
                    bool desc = ((i & size) == 0);
                    if (desc ? !inOrder : inOrder) { ss[i] = b; ss[j] = a; si_[i] = ib; si_[j] = ia; }
                }
            }
        }
        __syncthreads();
        if (t < knext) kept[t] = si_[t];
        __syncthreads();
        {
            float mx = -INFINITY, sm = 0.f;
            for (int n = 0; n < knext; ++n) {
                int o = kept[n];
                float vv = P[(size_t)o * HF + t] * scoreV[o];
                Q[(size_t)n * HF + t] = vv;
                mx = fmaxf(mx, vv);
                sm += vv;
            }
            accMx += mx;
            accMn += sm / (float)knext;
        }
        rankOf[t] = -1;
        __syncthreads();
        if (t < knext) rankOf[kept[t]] = t;
        __syncthreads();
        { int c = curID[t]; curID[t] = (c >= 0) ? rankOf[c] : -1; }
        __syncthreads();
        { float* tmp = P; P = Q; Q = tmp; }
        npg = knext;
    }
    row[t] = accMx;
    row[256 + t] = accMn;
    __syncthreads();
    { float a = l1b[t]; for (int j = 0; j < 512; ++j) a += row[j] * l1w[j * 256 + t]; scoreV[t] = fmaxf(a, 0.f); }
    __syncthreads();
    if (t < 128) { float a2 = l2b[t]; for (int j = 0; j < 256; ++j) a2 += scoreV[j] * l2w[j * 128 + t]; sa[t] = fmaxf(a2, 0.f); }
    __syncthreads();
    if (t == 0) {
        float l0 = l3b[0], l1 = l3b[1];
        for (int j = 0; j < 128; ++j) { float h = sa[j]; l0 += h * l3w[j * 2 + 0]; l1 += h * l3w[j * 2 + 1]; }
        float m = fmaxf(l0, l1);
        float lse = m + logf(expf(l0 - m) + expf(l1 - m));
        out[g * 2 + 0] = l0 - lse;
        out[g * 2 + 1] = l1 - lse;
    }
}

// ============================================================================
extern "C" void kernel_launch(void* const* d_in, const int* in_sizes, int n_in,
                              void* d_out, int out_size, void* d_ws, size_t ws_size,
                              hipStream_t stream) {
    const float* x   = (const float*)d_in[0];
    const int*   ei  = (const int*)d_in[1];
    const float* gw0 = (const float*)d_in[3];
    const float* gb0 = (const float*)d_in[4];
    const float* gw1 = (const float*)d_in[5];
    const float* gb1 = (const float*)d_in[6];
    const float* gw2 = (const float*)d_in[7];
    const float* gb2 = (const float*)d_in[8];
    const float* pw0 = (const float*)d_in[9];
    const float* pw1 = (const float*)d_in[10];
    const float* pw2 = (const float*)d_in[11];
    const float* l1w = (const float*)d_in[12];
    const float* l1b = (const float*)d_in[13];
    const float* l2w = (const float*)d_in[14];
    const float* l2b = (const float*)d_in[15];
    const float* l3w = (const float*)d_in[16];
    const float* l3b = (const float*)d_in[17];
    float* out = (float*)d_out;

    const size_t SLAB = (size_t)65536 * 256;
    char* p = (char*)d_ws;
    float* P      = (float*)p; p += SLAB * 4;
    float* Q      = (float*)p; p += SLAB * 4;
    int*   cur    = (int*)p;   p += (size_t)65536 * 4;
    int*   degS   = (int*)p;   p += (size_t)65536 * 4;
    float* dinvS  = (float*)p; p += (size_t)65536 * 4;
    int*   starts = (int*)p;   p += (size_t)65536 * 4;
    int2*  slots2 = (int2*)p;  p += (size_t)E_TOT * 8;
    float* score  = (float*)p; p += (size_t)65536 * 4;
    int*   kept   = (int*)p;   p += (size_t)32768 * 4;
    float* outacc = (float*)p; p += (size_t)G_GRAPHS * 512 * 4;
    const size_t needed = (size_t)(p - (char*)d_ws);

    if (ws_size < needed) {
        gnn_mono<<<G_GRAPHS, 256, 0, stream>>>(
            x, ei, gw0, gb0, gw1, gb1, gw2, gb2, pw0, pw1, pw2,
            l1w, l1b, l2w, l2b, l3w, l3b, out, (float*)d_ws);
        return;
    }

    init_cur<<<(G_GRAPHS * 256 + 255) / 256, 256, 0, stream>>>(cur);

    const int   npg[3] = {256, 128, 64};
    const int   kk[3]  = {128, 64, 32};
    const int   Ns[3]  = {65536, 32768, 16384};
    const float* GW[3] = {gw0, gw1, gw2};
    const float* GB[3] = {gb0, gb1, gb2};
    const float* PW[3] = {pw0, pw1, pw2};

    float* HLs[3]   = {P, Q, P};
    float* H2s[3]   = {Q, P, Q};
    float* POOLs[3] = {P, Q, P};

    for (int s = 0; s < 3; ++s) {
        const int n = Ns[s];
        const int k = kk[s];
        // 1) GEMM
        if (s == 0) {
            dim3 grid(n / 64, 2);
            gemm_v2<FIN><<<grid, 256, 0, stream>>>(x, GW[s], HLs[s]);
        } else {
            dim3 grid(n / 64, 2);
            gemm_v2<HF><<<grid, 256, 0, stream>>>(POOLs[s - 1], GW[s], HLs[s]);
        }
        // 2) CSR (parallel stable counting sort, packed slots)
        csr_build<<<G_GRAPHS, 256, 0, stream>>>(ei, cur, npg[s],
                                                degS, dinvS, starts, slots2);
        // 3) conv + score (XCD swizzle + batched edge loads)
        agg_score<<<n, 256, 0, stream>>>(degS, dinvS, starts, slots2,
                                         HLs[s], H2s[s], GB[s], PW[s], score,
                                         n / 8);
        // 4) top-k + cur update
        topk_cur<<<G_GRAPHS, 256, 0, stream>>>(score, npg[s], k, kept, cur);
        // 5) pool
        pool_gather<<<G_GRAPHS * k, 256, 0, stream>>>(kept, score, H2s[s], POOLs[s]);
        // 6) readout
        readout<<<G_GRAPHS, 256, 0, stream>>>(POOLs[s], k, outacc, s == 0 ? 1 : 0);
    }

    mlp_head<<<G_GRAPHS, 256, 0, stream>>>(outacc, l1w, l1b, l2w, l2b, l3w, l3b, out);
}

// Round 22
// 553.805 us; speedup vs baseline: 2.1262x; 1.0088x over previous
//
#include <hip/hip_runtime.h>
#include <hip/hip_bf16.h>
#include <math.h>

#define G_GRAPHS 256
#define EPG 2048
#define E_TOT 524288
#define HF 256
#define FIN 128

// ============================================================================
__global__ void init_cur(int* __restrict__ cur) {
    int i = blockIdx.x * blockDim.x + threadIdx.x;
    if (i < G_GRAPHS * 256) cur[i] = i & 255;
}

// ---------------------------------------------------------------------------
// C[N x 256] = A[N x K] @ W[K x 256], fp32, k-ascending accumulation.
// 64x128 tile, 4x8/thread. W staged in TWO half arrays [kk][68] (odd quad
// stride) so b128 reads are 2-way max (free). Thread covers cols
// {c0+tx*4..+3} and {c0+64+tx*4..+3}; per-column chains unchanged.
// ---------------------------------------------------------------------------
template <int K>
__global__ __launch_bounds__(256)
void gemm_v3(const float* __restrict__ A, const float* __restrict__ W,
             float* __restrict__ C) {
    __shared__ float As2[64 * 65];
    __shared__ float Wa[64 * 68];
    __shared__ float Wb[64 * 68];
    const int tid = threadIdx.x;
    const int tx = tid & 15;
    const int ty = tid >> 4;
    const int r0 = blockIdx.x * 64;
    const int c0 = blockIdx.y * 128;
    float acc[4][8] = {{0.f}};
    for (int k0 = 0; k0 < K; k0 += 64) {
        // stage A: 64 rows x 64 kk (float4 global, scalar LDS, [row][65])
        {
            int r = tid >> 4;
            int c = tid & 15;
#pragma unroll
            for (int it = 0; it < 4; ++it) {
                float4 v = *(const float4*)&A[(size_t)(r0 + r) * K + k0 + 4 * c];
                float* dst = &As2[r * 65 + 4 * c];
                dst[0] = v.x; dst[1] = v.y; dst[2] = v.z; dst[3] = v.w;
                r += 16;
            }
        }
        // stage W: 64 kk x 128 cols -> split halves
        {
            int kk = tid >> 5;
            int c = tid & 31;
#pragma unroll
            for (int it = 0; it < 8; ++it) {
                float4 v = *(const float4*)&W[(size_t)(k0 + kk) * 256 + c0 + 4 * c];
                if (c < 16) *(float4*)&Wa[kk * 68 + 4 * c] = v;
                else        *(float4*)&Wb[kk * 68 + 4 * (c - 16)] = v;
                kk += 8;
            }
        }
        __syncthreads();
#pragma unroll 4
        for (int kk = 0; kk < 64; ++kk) {
            float av0 = As2[(ty * 4 + 0) * 65 + kk];
            float av1 = As2[(ty * 4 + 1) * 65 + kk];
            float av2 = As2[(ty * 4 + 2) * 65 + kk];
            float av3 = As2[(ty * 4 + 3) * 65 + kk];
            float4 w0 = *(const float4*)&Wa[kk * 68 + tx * 4];
            float4 w1 = *(const float4*)&Wb[kk * 68 + tx * 4];
            float wv[8] = {w0.x, w0.y, w0.z, w0.w, w1.x, w1.y, w1.z, w1.w};
#pragma unroll
            for (int cc = 0; cc < 8; ++cc) {
                acc[0][cc] += av0 * wv[cc];
                acc[1][cc] += av1 * wv[cc];
                acc[2][cc] += av2 * wv[cc];
                acc[3][cc] += av3 * wv[cc];
            }
        }
        __syncthreads();
    }
#pragma unroll
    for (int i = 0; i < 4; ++i) {
        float4 v0 = make_float4(acc[i][0], acc[i][1], acc[i][2], acc[i][3]);
        float4 v1 = make_float4(acc[i][4], acc[i][5], acc[i][6], acc[i][7]);
        size_t base = (size_t)(r0 + ty * 4 + i) * 256 + c0 + tx * 4;
        *(float4*)&C[base] = v0;
        *(float4*)&C[base + 64] = v1;
    }
}

// ---------------------------------------------------------------------------
// Parallel STABLE counting-sort CSR with packed (src, dinv_src) slots.
// ---------------------------------------------------------------------------
__global__ __launch_bounds__(256)
void csr_build(const int* __restrict__ ei, const int* __restrict__ cur, int npg,
               int* __restrict__ degS, float* __restrict__ dinvS,
               int* __restrict__ startsS, int2* __restrict__ slots2) {
    __shared__ int cul[EPG];
    __shared__ short dstv[EPG];
    __shared__ unsigned char rnk[EPG];
    __shared__ int h[32][256];
    __shared__ int cnt[256];
    __shared__ int st[256];
    const int g = blockIdx.x;
    const int t = threadIdx.x;
    const int lane = t & 63;
    const int wv = t >> 6;

    for (int i = t; i < 32 * 256; i += 256) ((int*)h)[i] = 0;
    for (int e = t; e < EPG; e += 256) {
        size_t idx = (size_t)g * EPG + e;
        int cu = cur[g * 256 + (ei[idx] - g * 256)];
        int cv = cur[g * 256 + (ei[E_TOT + idx] - g * 256)];
        bool valid = (cu >= 0 && cv >= 0);
        cul[e] = cu;
        dstv[e] = valid ? (short)cv : (short)256;
    }
    __syncthreads();
    for (int c = wv; c < 32; c += 4) {
        int e = c * 64 + lane;
        int d = (int)dstv[e];
        unsigned long long m = ~0ULL;
#pragma unroll
        for (int b = 0; b < 9; ++b) {
            unsigned long long bb = __ballot((d >> b) & 1);
            m &= ((d >> b) & 1) ? bb : ~bb;
        }
        int r = __popcll(m & ((1ULL << lane) - 1ULL));
        rnk[e] = (unsigned char)r;
        if (r == 0 && d < 256) h[c][d] = __popcll(m);
    }
    __syncthreads();
    if (t < npg) {
        int run = 0;
        for (int c = 0; c < 32; ++c) { int v = h[c][t]; h[c][t] = run; run += v; }
        cnt[t] = run;
        degS[g * npg + t] = run + 1;
        dinvS[g * npg + t] = 1.0f / sqrtf((float)(run + 1));
    }
    __syncthreads();
    if (t == 0) {
        int run = 0;
        for (int i = 0; i < npg; ++i) { st[i] = run; run += cnt[i]; }
    }
    __syncthreads();
    if (t < npg) startsS[g * npg + t] = g * EPG + st[t];
    for (int e = t; e < EPG; e += 256) {
        int d = (int)dstv[e];
        if (d < npg) {
            int slot = st[d] + h[e >> 6][d] + (int)rnk[e];
            int cu = cul[e];
            float dv = 1.0f / sqrtf((float)(cnt[cu] + 1));   // == dinvS[src]
            slots2[g * EPG + slot] = make_int2(g * npg + cu, __float_as_int(dv));
        }
    }
}

// ---------------------------------------------------------------------------
// conv + relu + pool score: XCD swizzle + batched (8/4/1) edge loads.
// ---------------------------------------------------------------------------
__global__ __launch_bounds__(256)
void agg_score(const int* __restrict__ degS, const float* __restrict__ dinvS,
               const int* __restrict__ startsS, const int2* __restrict__ slots2,
               const float* __restrict__ HL, float* __restrict__ H2,
               const float* __restrict__ bias, const float* __restrict__ pw,
               float* __restrict__ score, int nOver8) {
    __shared__ float vrow[256];
    const int node = (blockIdx.x & 7) * nOver8 + (blockIdx.x >> 3);
    const int t = threadIdx.x;
    const int cntE = degS[node] - 1;
    const float degF = (float)degS[node];
    const float dn = dinvS[node];
    const int2* sl = slots2 + startsS[node];
    float acc = 0.f;
    int j = 0;
    for (; j + 8 <= cntE; j += 8) {
        int2 s[8];
#pragma unroll
        for (int u = 0; u < 8; ++u) s[u] = sl[j + u];
        float hv[8];
#pragma unroll
        for (int u = 0; u < 8; ++u) hv[u] = HL[(size_t)s[u].x * 256 + t];
#pragma unroll
        for (int u = 0; u < 8; ++u) acc += __int_as_float(s[u].y) * hv[u];
    }
    for (; j + 4 <= cntE; j += 4) {
        int2 s[4];
#pragma unroll
        for (int u = 0; u < 4; ++u) s[u] = sl[j + u];
        float hv[4];
#pragma unroll
        for (int u = 0; u < 4; ++u) hv[u] = HL[(size_t)s[u].x * 256 + t];
#pragma unroll
        for (int u = 0; u < 4; ++u) acc += __int_as_float(s[u].y) * hv[u];
    }
    for (; j < cntE; ++j) {
        int2 sv = sl[j];
        acc += __int_as_float(sv.y) * HL[(size_t)sv.x * 256 + t];
    }
    float v = acc * dn + HL[(size_t)node * 256 + t] / degF + bias[t];
    v = fmaxf(v, 0.f);
    H2[(size_t)node * 256 + t] = v;
    vrow[t] = v;
    __syncthreads();
    if (t < 64) {
        const int lane = t;
        float pr = 0.f, s2p = 0.f;
        for (int jj = 0; jj < 4; ++jj) {
            int f = lane + 64 * jj;
            float w = pw[f];
            pr += vrow[f] * w;
            s2p += w * w;
        }
        for (int off = 32; off; off >>= 1) {
            pr += __shfl_down(pr, off, 64);
            s2p += __shfl_down(s2p, off, 64);
        }
        s2p = __shfl(s2p, 0, 64);
        if (lane == 0) score[node] = tanhf(pr / sqrtf(s2p));
    }
}

// ---------------------------------------------------------------------------
__global__ __launch_bounds__(256)
void topk_cur(const float* __restrict__ score, int npg, int k,
              int* __restrict__ kept, int* __restrict__ cur) {
    __shared__ float ss[256];
    __shared__ int si_[256];
    __shared__ int rankOf[256];
    const int g = blockIdx.x;
    const int t = threadIdx.x;
    if (t < npg) { ss[t] = score[g * npg + t]; si_[t] = t; }
    else         { ss[t] = -INFINITY; si_[t] = 0x7FFFFFFF; }
    for (int size = 2; size <= 256; size <<= 1) {
        for (int stride = size >> 1; stride > 0; stride >>= 1) {
            __syncthreads();
            int i = t, j = t ^ stride;
            if (j > i) {
                float a = ss[i], b = ss[j];
                int ia = si_[i], ib = si_[j];
                bool inOrder = (a > b) || (a == b && ia < ib);
                bool desc = ((i & size) == 0);
                if (desc ? !inOrder : inOrder) {
                    ss[i] = b; ss[j] = a; si_[i] = ib; si_[j] = ia;
                }
            }
        }
    }
    __syncthreads();
    rankOf[t] = -1;
    __syncthreads();
    if (t < k) {
        kept[g * k + t] = g * npg + si_[t];
        rankOf[si_[t]] = t;
    }
    __syncthreads();
    {
        int v = g * 256 + t;
        int c = cur[v];
        cur[v] = (c >= 0) ? rankOf[c] : -1;
    }
}

__global__ __launch_bounds__(256)
void pool_gather(const int* __restrict__ kept, const float* __restrict__ score,
                 const float* __restrict__ H2, float* __restrict__ OUT) {
    const int j = blockIdx.x;
    const int t = threadIdx.x;
    const int o = kept[j];
    OUT[(size_t)j * 256 + t] = H2[(size_t)o * 256 + t] * score[o];
}

__global__ __launch_bounds__(256)
void readout(const float* __restrict__ X, int k, float* __restrict__ outacc,
             int first) {
    const int g = blockIdx.x;
    const int t = threadIdx.x;
    const float* base = X + (size_t)g * k * 256 + t;
    float mx = -INFINITY, sm = 0.f;
    for (int n = 0; n < k; ++n) {
        float vv = base[(size_t)n * 256];
        mx = fmaxf(mx, vv);
        sm += vv;
    }
    float mean = sm / (float)k;
    if (first) {
        outacc[g * 512 + t] = mx;
        outacc[g * 512 + 256 + t] = mean;
    } else {
        outacc[g * 512 + t] += mx;
        outacc[g * 512 + 256 + t] += mean;
    }
}

__global__ __launch_bounds__(256)
void mlp_head(const float* __restrict__ outacc,
              const float* __restrict__ l1w, const float* __restrict__ l1b,
              const float* __restrict__ l2w, const float* __restrict__ l2b,
              const float* __restrict__ l3w, const float* __restrict__ l3b,
              float* __restrict__ out) {
    __shared__ float row[512];
    __shared__ float h1[256];
    __shared__ float h2[128];
    const int g = blockIdx.x;
    const int t = threadIdx.x;
    row[t] = outacc[g * 512 + t];
    row[256 + t] = outacc[g * 512 + 256 + t];
    __syncthreads();
    {
        float a = l1b[t];
        for (int j = 0; j < 512; ++j) a += row[j] * l1w[j * 256 + t];
        h1[t] = fmaxf(a, 0.f);
    }
    __syncthreads();
    if (t < 128) {
        float a2 = l2b[t];
        for (int j = 0; j < 256; ++j) a2 += h1[j] * l2w[j * 128 + t];
        h2[t] = fmaxf(a2, 0.f);
    }
    __syncthreads();
    if (t == 0) {
        float l0 = l3b[0], l1 = l3b[1];
        for (int j = 0; j < 128; ++j) {
            float h = h2[j];
            l0 += h * l3w[j * 2 + 0];
            l1 += h * l3w[j * 2 + 1];
        }
        float m = fmaxf(l0, l1);
        float lse = m + logf(expf(l0 - m) + expf(l1 - m));
        out[g * 2 + 0] = l0 - lse;
        out[g * 2 + 1] = l1 - lse;
    }
}

// ============================================================================
// Fallback: proven R15 monolith (used only if ws_size is too small)
// ============================================================================
__global__ __launch_bounds__(256, 1)
void gnn_mono(const float* __restrict__ x, const int* __restrict__ ei,
              const float* __restrict__ gw0, const float* __restrict__ gb0,
              const float* __restrict__ gw1, const float* __restrict__ gb1,
              const float* __restrict__ gw2, const float* __restrict__ gb2,
              const float* __restrict__ pw0, const float* __restrict__ pw1,
              const float* __restrict__ pw2,
              const float* __restrict__ l1w, const float* __restrict__ l1b,
              const float* __restrict__ l2w, const float* __restrict__ l2b,
              const float* __restrict__ l3w, const float* __restrict__ l3b,
              float* __restrict__ out, float* __restrict__ ws) {
    const int g = blockIdx.x;
    const int t = threadIdx.x;
    float* P = ws + (size_t)g * HF * 256;
    float* Q = ws + (size_t)G_GRAPHS * HF * 256 + (size_t)g * HF * 256;
    __shared__ int   eb[EPG];
    __shared__ int   slots[EPG];
    __shared__ int   curID[256];
    __shared__ int   cntL[256];
    __shared__ int   startL[256];
    __shared__ float degF[256];
    __shared__ float dinv[256];
    __shared__ float sa[256];
    __shared__ float ss[256];
    __shared__ int   si_[256];
    __shared__ float scoreV[256];
    __shared__ int   kept[128];
    __shared__ int   rankOf[256];
    __shared__ float row[512];
    for (int e = t; e < EPG; e += 256) {
        size_t idx = (size_t)g * EPG + e;
        eb[e] = ((ei[idx] - g * 256) << 8) | (ei[E_TOT + idx] - g * 256);
    }
    curID[t] = t;
    float accMx = 0.f, accMn = 0.f;
    const float* GW[3] = {gw0, gw1, gw2};
    const float* GB[3] = {gb0, gb1, gb2};
    const float* PW[3] = {pw0, pw1, pw2};
    const int kk[3] = {128, 64, 32};
    int npg = 256;
    __syncthreads();
    for (int s = 0; s < 3; ++s) {
        const int knext = kk[s];
        {
            const float* Wp = GW[s];
            const int K = (s == 0) ? FIN : HF;
            for (int n = 0; n < npg; ++n) {
                if (s == 0) { if (t < FIN) sa[t] = x[(size_t)(g * 256 + n) * FIN + t]; }
                else sa[t] = P[(size_t)n * HF + t];
                __syncthreads();
                float a = 0.f;
                for (int k2 = 0; k2 < K; ++k2) a += sa[k2] * Wp[k2 * HF + t];
                Q[(size_t)n * HF + t] = a;
                __syncthreads();
            }
        }
        cntL[t] = 0;
        __syncthreads();
        for (int e = t; e < EPG; e += 256) {
            int p = eb[e];
            int cu = curID[p >> 8], cv = curID[p & 255];
            if (cu >= 0 && cv >= 0) atomicAdd(&cntL[cv], 1);
        }
        __syncthreads();
        if (t == 0) { int run = 0; for (int i = 0; i < npg; ++i) { startL[i] = run; run += cntL[i]; } }
        __syncthreads();
        if (t < npg) {
            float d = (float)cntL[t] + 1.0f;
            degF[t] = d;
            dinv[t] = 1.0f / sqrtf(d);
            int c = startL[t];
            for (int e = 0; e < EPG; ++e) {
                int p = eb[e];
                int cu = curID[p >> 8], cv = curID[p & 255];
                if (cu >= 0 && cv >= 0 && cv == t) slots[c++] = e;
            }
        }
        __syncthreads();
        {
            const float bb = GB[s][t];
            for (int n = 0; n < npg; ++n) {
                float acc = 0.f;
                const int s0 = startL[n], s1 = s0 + cntL[n];
                for (int j = s0; j < s1; ++j) {
                    int scur = curID[eb[slots[j]] >> 8];
                    acc += dinv[scur] * Q[(size_t)scur * HF + t];
                }
                float v = acc * dinv[n] + Q[(size_t)n * HF + t] / degF[n] + bb;
                P[(size_t)n * HF + t] = fmaxf(v, 0.f);
            }
        }
        __syncthreads();
        {
            const float* pwp = PW[s];
            const int lane = t & 63, wv = t >> 6;
            float s2p = 0.f;
            for (int j = 0; j < 4; ++j) { float w = pwp[lane + 64 * j]; s2p += w * w; }
            for (int off = 32; off; off >>= 1) s2p += __shfl_down(s2p, off, 64);
            s2p = __shfl(s2p, 0, 64);
            const float nw = sqrtf(s2p);
            for (int n = wv; n < npg; n += 4) {
                float pr = 0.f;
                for (int j = 0; j < 4; ++j) { int f = lane + 64 * j; pr += P[(size_t)n * HF + f] * pwp[f]; }
                for (int off = 32; off; off >>= 1) pr += __shfl_down(pr, off, 64);
                if (lane == 0) scoreV[n] = tanhf(pr / nw);
            }
        }
        __syncthreads();
        if (t < npg) { ss[t] = scoreV[t]; si_[t] = t; }
        else         { ss[t] = -INFINITY; si_[t] = 0x7FFFFFFF; }
        for (int size = 2; size <= 256; size <<= 1) {
            for (int stride = size >> 1; stride > 0; stride >>= 1) {
                __syncthreads();
                int i = t, j = t ^ stride;
                if (j > i) {
                    float a = ss[i], b = ss[j];
                    int ia = si_[i], ib = si_[j];
                    bool inOrder = (a > b) || (a == b && ia < ib);
                    bool desc = ((i & size) == 0);
                    if (desc ? !inOrder : inOrder) { ss[i] = b; ss[j] = a; si_[i] = ib; si_[j] = ia; }
                }
            }
        }
        __syncthreads();
        if (t < knext) kept[t] = si_[t];
        __syncthreads();
        {
            float mx = -INFINITY, sm = 0.f;
            for (int n = 0; n < knext; ++n) {
                int o = kept[n];
                float vv = P[(size_t)o * HF + t] * scoreV[o];
                Q[(size_t)n * HF + t] = vv;
                mx = fmaxf(mx, vv);
                sm += vv;
            }
            accMx += mx;
            accMn += sm / (float)knext;
        }
        rankOf[t] = -1;
        __syncthreads();
        if (t < knext) rankOf[kept[t]] = t;
        __syncthreads();
        { int c = curID[t]; curID[t] = (c >= 0) ? rankOf[c] : -1; }
        __syncthreads();
        { float* tmp = P; P = Q; Q = tmp; }
        npg = knext;
    }
    row[t] = accMx;
    row[256 + t] = accMn;
    __syncthreads();
    { float a = l1b[t]; for (int j = 0; j < 512; ++j) a += row[j] * l1w[j * 256 + t]; scoreV[t] = fmaxf(a, 0.f); }
    __syncthreads();
    if (t < 128) { float a2 = l2b[t]; for (int j = 0; j < 256; ++j) a2 += scoreV[j] * l2w[j * 128 + t]; sa[t] = fmaxf(a2, 0.f); }
    __syncthreads();
    if (t == 0) {
        float l0 = l3b[0], l1 = l3b[1];
        for (int j = 0; j < 128; ++j) { float h = sa[j]; l0 += h * l3w[j * 2 + 0]; l1 += h * l3w[j * 2 + 1]; }
        float m = fmaxf(l0, l1);
        float lse = m + logf(expf(l0 - m) + expf(l1 - m));
        out[g * 2 + 0] = l0 - lse;
        out[g * 2 + 1] = l1 - lse;
    }
}

// ============================================================================
extern "C" void kernel_launch(void* const* d_in, const int* in_sizes, int n_in,
                              void* d_out, int out_size, void* d_ws, size_t ws_size,
                              hipStream_t stream) {
    const float* x   = (const float*)d_in[0];
    const int*   ei  = (const int*)d_in[1];
    const float* gw0 = (const float*)d_in[3];
    const float* gb0 = (const float*)d_in[4];
    const float* gw1 = (const float*)d_in[5];
    const float* gb1 = (const float*)d_in[6];
    const float* gw2 = (const float*)d_in[7];
    const float* gb2 = (const float*)d_in[8];
    const float* pw0 = (const float*)d_in[9];
    const float* pw1 = (const float*)d_in[10];
    const float* pw2 = (const float*)d_in[11];
    const float* l1w = (const float*)d_in[12];
    const float* l1b = (const float*)d_in[13];
    const float* l2w = (const float*)d_in[14];
    const float* l2b = (const float*)d_in[15];
    const float* l3w = (const float*)d_in[16];
    const float* l3b = (const float*)d_in[17];
    float* out = (float*)d_out;

    const size_t SLAB = (size_t)65536 * 256;
    char* p = (char*)d_ws;
    float* P      = (float*)p; p += SLAB * 4;
    float* Q      = (float*)p; p += SLAB * 4;
    int*   cur    = (int*)p;   p += (size_t)65536 * 4;
    int*   degS   = (int*)p;   p += (size_t)65536 * 4;
    float* dinvS  = (float*)p; p += (size_t)65536 * 4;
    int*   starts = (int*)p;   p += (size_t)65536 * 4;
    int2*  slots2 = (int2*)p;  p += (size_t)E_TOT * 8;
    float* score  = (float*)p; p += (size_t)65536 * 4;
    int*   kept   = (int*)p;   p += (size_t)32768 * 4;
    float* outacc = (float*)p; p += (size_t)G_GRAPHS * 512 * 4;
    const size_t needed = (size_t)(p - (char*)d_ws);

    if (ws_size < needed) {
        gnn_mono<<<G_GRAPHS, 256, 0, stream>>>(
            x, ei, gw0, gb0, gw1, gb1, gw2, gb2, pw0, pw1, pw2,
            l1w, l1b, l2w, l2b, l3w, l3b, out, (float*)d_ws);
        return;
    }

    init_cur<<<(G_GRAPHS * 256 + 255) / 256, 256, 0, stream>>>(cur);

    const int   npg[3] = {256, 128, 64};
    const int   kk[3]  = {128, 64, 32};
    const int   Ns[3]  = {65536, 32768, 16384};
    const float* GW[3] = {gw0, gw1, gw2};
    const float* GB[3] = {gb0, gb1, gb2};
    const float* PW[3] = {pw0, pw1, pw2};

    float* HLs[3]   = {P, Q, P};
    float* H2s[3]   = {Q, P, Q};
    float* POOLs[3] = {P, Q, P};

    for (int s = 0; s < 3; ++s) {
        const int n = Ns[s];
        const int k = kk[s];
        // 1) GEMM (split-half W staging: conflict-free b128 reads)
        if (s == 0) {
            dim3 grid(n / 64, 2);
            gemm_v3<FIN><<<grid, 256, 0, stream>>>(x, GW[s], HLs[s]);
        } else {
            dim3 grid(n / 64, 2);
            gemm_v3<HF><<<grid, 256, 0, stream>>>(POOLs[s - 1], GW[s], HLs[s]);
        }
        // 2) CSR (parallel stable counting sort, packed slots)
        csr_build<<<G_GRAPHS, 256, 0, stream>>>(ei, cur, npg[s],
                                                degS, dinvS, starts, slots2);
        // 3) conv + score (XCD swizzle + batched edge loads)
        agg_score<<<n, 256, 0, stream>>>(degS, dinvS, starts, slots2,
                                         HLs[s], H2s[s], GB[s], PW[s], score,
                                         n / 8);
        // 4) top-k + cur update
        topk_cur<<<G_GRAPHS, 256, 0, stream>>>(score, npg[s], k, kept, cur);
        // 5) pool
        pool_gather<<<G_GRAPHS * k, 256, 0, stream>>>(kept, score, H2s[s], POOLs[s]);
        // 6) readout
        readout<<<G_GRAPHS, 256, 0, stream>>>(POOLs[s], k, outacc, s == 0 ? 1 : 0);
    }

    mlp_head<<<G_GRAPHS, 256, 0, stream>>>(outacc, l1w, l1b, l2w, l2b, l3w, l3b, out);
}